// Round 9
// baseline (264.195 us; speedup 1.0000x reference)
//
#include <hip/hip_runtime.h>
#include <cmath>

typedef unsigned short u16;
typedef unsigned int   u32;
typedef __attribute__((ext_vector_type(8))) short bf16x8;  // 8 bf16 in 4 VGPRs
typedef __attribute__((ext_vector_type(4))) float f32x4;   // MFMA accumulator

#define DEV __device__ __forceinline__
#define MFMA(a,b,c) __builtin_amdgcn_mfma_f32_16x16x32_bf16((a),(b),(c),0,0,0)

// async global->LDS, 16B per lane: lane l writes dst + l*16 bytes (dst wave-uniform)
#define GLOAD16(dst, src) __builtin_amdgcn_global_load_lds( \
    (const __attribute__((address_space(1))) void*)(src), \
    (__attribute__((address_space(3))) void*)(dst), 16, 0, 0)

// ---- bf16 helpers (RNE) ----
DEV u16 f2bf(float x){ union{float f;u32 u;} v; v.f=x; u32 r=v.u+0x7FFFu+((v.u>>16)&1u); return (u16)(r>>16); }
DEV float bf2f(u16 h){ union{u32 u;float f;} v; v.u=((u32)h)<<16; return v.f; }

// LDS read-side swizzle: within a row (64 elems = 8 col-blocks of 8), XOR the
// col-block with row&7. Same involution applied to the gload SOURCE col, so
// LDS dest stays linear (rule #21). Verified on HW (rounds 7-8: conflicts=0,
// absmax unchanged).
DEV int swz(int row, int cb){ return row*64 + ((cb ^ (row&7))*8); }

// ============================================================================
// prep kernels
// ============================================================================

// in fp32 [R][C] -> hi bf16 [C][R] (+ optional lo = bf16(x - hi))
__global__ __launch_bounds__(256) void k_transpose(const float* __restrict__ in,
        u16* __restrict__ hi, u16* __restrict__ lo, int R, int C){
    __shared__ float t[32][33];
    const int r0 = blockIdx.y*32, c0 = blockIdx.x*32;
    const int lr = threadIdx.x>>3, lc = (threadIdx.x&7)*4;
    float4 v = *(const float4*)(in + (size_t)(r0+lr)*C + c0 + lc);
    t[lr][lc]=v.x; t[lr][lc+1]=v.y; t[lr][lc+2]=v.z; t[lr][lc+3]=v.w;
    __syncthreads();
    float vals[4]; u16 h[4];
    #pragma unroll
    for(int j=0;j<4;++j){ vals[j]=t[lc+j][lr]; h[j]=f2bf(vals[j]); }
    ushort4 o; o.x=h[0]; o.y=h[1]; o.z=h[2]; o.w=h[3];
    *(ushort4*)(hi + (size_t)(c0+lr)*R + r0+lc) = o;
    if (lo){
        ushort4 q; q.x=f2bf(vals[0]-bf2f(h[0])); q.y=f2bf(vals[1]-bf2f(h[1]));
        q.z=f2bf(vals[2]-bf2f(h[2])); q.w=f2bf(vals[3]-bf2f(h[3]));
        *(ushort4*)(lo + (size_t)(c0+lr)*R + r0+lc) = q;
    }
}

// proj [64 d][256 m] fp32 -> packed B-fragments hi/lo:
// pPh[((nt*2+ks)*64 + lane)*8 + e] = bf16(proj[32*ks+8*(lane/16)+e][16*nt+lane%16])
__global__ __launch_bounds__(256) void k_pack_proj(const float* __restrict__ proj,
        u16* __restrict__ ph, u16* __restrict__ pl){
    int idx = blockIdx.x*256 + threadIdx.x;       // 0..16383
    int e = idx&7, l = (idx>>3)&63, f = idx>>9;   // f = nt*2+ks
    int nt = f>>1, ks = f&1;
    int d = 32*ks + 8*(l>>4) + e;
    int m = 16*nt + (l&15);
    float x = proj[d*256 + m];
    u16 h = f2bf(x);
    ph[idx] = h; pl[idx] = f2bf(x - bf2f(h));
}

__global__ __launch_bounds__(256) void k_convertX(const float* __restrict__ X, u16* __restrict__ Xb){
    size_t i = ((size_t)blockIdx.x*256 + threadIdx.x)*4;
    float4 v = *(const float4*)(X+i);
    ushort4 o; o.x=f2bf(v.x); o.y=f2bf(v.y); o.z=f2bf(v.z); o.w=f2bf(v.w);
    *(ushort4*)(Xb+i) = o;
}

// ============================================================================
// k_qkv (m201 geometry): C = X @ {Wq,Wk,Wv}, BM=BN=256, BK=64.
// 512 thr = 8 waves (2M x 4N), per-wave 128x64 out = acc[8][4]. 2 LDS slots.
// Per tile: 2 halves x 32 MFMA, 2 barriers. Stage units (64x64, 1 gload x 512):
//   half0 issues B0,B1,A0,B2,B3,A2 (kt+1); half1 issues A1,A3 (kt+1).
// vmcnt(6) end-half0 (certifies THIS tile's A1,A3, issued 1 half ago);
// vmcnt(2) end-half1 (certifies next tile's 6 entry units). Never 0 till drain.
// grid (32, 12): y/4 = wsel, y%4 = 256-col block.
// ============================================================================
__global__ __launch_bounds__(512,2) void k_qkv(const u16* __restrict__ Xb, const u16* __restrict__ WT,
        const float* __restrict__ bq, const float* __restrict__ bk, const float* __restrict__ bv,
        float* __restrict__ Qn, float* __restrict__ Kn, u16* __restrict__ VT){
    __shared__ u16 As[2*256*64];   // 64KB
    __shared__ u16 Bs[2*256*64];   // 64KB
    const int bx = blockIdx.x, y = blockIdx.y;
    const int wsel = y>>2, nb = y&3;
    const int tid = threadIdx.x, w = tid>>6, l = tid&63, g = l>>4, c = l&15;
    const int wr = w>>2, wc = w&3;
    const u16* Ap = Xb + (size_t)bx*256*1024;
    const u16* Bp = WT + (size_t)wsel*1048576 + (size_t)nb*256*1024;
    const int srow_ = w*8 + (l>>3);
    const int scol_ = ((l&7) ^ (l>>3))*8;
#define SA(slot,j,k0) GLOAD16(&As[(slot)*(256*64) + ((j)*64 + w*8)*64], Ap + (size_t)((j)*64 + srow_)*1024 + (k0) + scol_)
#define SB(slot,j,k0) GLOAD16(&Bs[(slot)*(256*64) + ((j)*64 + w*8)*64], Bp + (size_t)((j)*64 + srow_)*1024 + (k0) + scol_)
    f32x4 acc[8][4];
    #pragma unroll
    for(int mt=0;mt<8;++mt)
        #pragma unroll
        for(int nt=0;nt<4;++nt) acc[mt][nt] = f32x4{0.f,0.f,0.f,0.f};
    // prologue: tile0 -> slot0, order B0,B1,A0,B2,B3,A2,A1,A3
    SB(0,0,0); SB(0,1,0); SA(0,0,0); SB(0,2,0); SB(0,3,0); SA(0,2,0); SA(0,1,0); SA(0,3,0);
    asm volatile("s_waitcnt vmcnt(2)" ::: "memory");
    __builtin_amdgcn_s_barrier();
    __builtin_amdgcn_sched_barrier(0);
    for(int kt=0; kt<16; ++kt){
        const int cur = kt&1, nx = cur^1, k2 = (kt+1)*64;
        const bool more = kt < 15;
        const u16* Asl = As + cur*(256*64);
        const u16* Bsl = Bs + cur*(256*64);
        // ---- half 0: mt 0..3 ----
        bf16x8 bf_[4][2];
        #pragma unroll
        for(int nt=0;nt<4;++nt)
            #pragma unroll
            for(int ks=0;ks<2;++ks)
                bf_[nt][ks] = *(const bf16x8*)&Bsl[swz(64*wc+16*nt+c, 4*ks+g)];
        if(more){ SB(nx,0,k2); SB(nx,1,k2); SA(nx,0,k2); SB(nx,2,k2); SB(nx,3,k2); SA(nx,2,k2); }
        __builtin_amdgcn_s_setprio(1);
        #pragma unroll
        for(int mt=0;mt<4;++mt){
            bf16x8 a0 = *(const bf16x8*)&Asl[swz(128*wr+16*mt+c, g)];
            bf16x8 a1 = *(const bf16x8*)&Asl[swz(128*wr+16*mt+c, 4+g)];
            #pragma unroll
            for(int nt=0;nt<4;++nt){
                acc[mt][nt] = MFMA(a0, bf_[nt][0], acc[mt][nt]);
                acc[mt][nt] = MFMA(a1, bf_[nt][1], acc[mt][nt]);
            }
        }
        __builtin_amdgcn_s_setprio(0);
        if(more) asm volatile("s_waitcnt vmcnt(6)" ::: "memory");
        else     asm volatile("s_waitcnt vmcnt(0)" ::: "memory");
        __builtin_amdgcn_s_barrier();
        __builtin_amdgcn_sched_barrier(0);
        // ---- half 1: mt 4..7 ----
        if(more){ SA(nx,1,k2); SA(nx,3,k2); }
        __builtin_amdgcn_s_setprio(1);
        #pragma unroll
        for(int mt=4;mt<8;++mt){
            bf16x8 a0 = *(const bf16x8*)&Asl[swz(128*wr+16*mt+c, g)];
            bf16x8 a1 = *(const bf16x8*)&Asl[swz(128*wr+16*mt+c, 4+g)];
            #pragma unroll
            for(int nt=0;nt<4;++nt){
                acc[mt][nt] = MFMA(a0, bf_[nt][0], acc[mt][nt]);
                acc[mt][nt] = MFMA(a1, bf_[nt][1], acc[mt][nt]);
            }
        }
        __builtin_amdgcn_s_setprio(0);
        if(more) asm volatile("s_waitcnt vmcnt(2)" ::: "memory");
        __builtin_amdgcn_s_barrier();
        __builtin_amdgcn_sched_barrier(0);
    }
#undef SA
#undef SB
    const int n0 = nb*256 + 64*wc;    // col within this wsel's 1024
    const int b = bx>>4;
    if (wsel < 2){
        float* Out = wsel ? Kn : Qn;
        const float* bias = wsel ? bk : bq;
        float bb[4];
        #pragma unroll
        for(int nt=0;nt<4;++nt) bb[nt] = bias[n0+16*nt+c];
        #pragma unroll
        for(int mt=0;mt<8;++mt){
            #pragma unroll
            for(int nt=0;nt<4;++nt)
                #pragma unroll
                for(int r=0;r<4;++r) acc[mt][nt][r] += bb[nt];
            // wave's 64 cols are one head -> norm over nt(4) x shfl16
            #pragma unroll
            for(int r=0;r<4;++r){
                float ss = 0.f;
                #pragma unroll
                for(int nt=0;nt<4;++nt){ float vv = acc[mt][nt][r]; ss += vv*vv; }
                ss += __shfl_xor(ss,1); ss += __shfl_xor(ss,2);
                ss += __shfl_xor(ss,4); ss += __shfl_xor(ss,8);
                float sc = 1.f/(sqrtf(ss)+1e-6f);
                #pragma unroll
                for(int nt=0;nt<4;++nt) acc[mt][nt][r] *= sc;
            }
            const int rowb = bx*256 + 128*wr + 16*mt + 4*g;
            #pragma unroll
            for(int nt=0;nt<4;++nt)
                #pragma unroll
                for(int r=0;r<4;++r)
                    Out[(size_t)(rowb+r)*1024 + n0 + 16*nt + c] = acc[mt][nt][r];
        }
    } else {
        const int h = nb*4 + wc;
        float bb[4];
        #pragma unroll
        for(int nt=0;nt<4;++nt) bb[nt] = bv[n0+16*nt+c];
        #pragma unroll
        for(int mt=0;mt<8;++mt)
            #pragma unroll
            for(int nt=0;nt<4;++nt){
                const int d = 16*nt + c;
                const int s0m = (bx&15)*256 + 128*wr + 16*mt + 4*g;
                ushort4 o;
                o.x = f2bf(acc[mt][nt][0]+bb[nt]); o.y = f2bf(acc[mt][nt][1]+bb[nt]);
                o.z = f2bf(acc[mt][nt][2]+bb[nt]); o.w = f2bf(acc[mt][nt][3]+bb[nt]);
                *(ushort4*)(VT + ((size_t)(b*16+h)*64 + d)*4096 + s0m) = o;
            }
    }
}

// ============================================================================
// k_kv: per (chunk, b*16+h): KV[m,d] = sum_s phiK[s,m] V[s,d]; Z[m] = sum_s phiK
// Split-K over 16 chunks of 256 s. grid (16, 32), 4 waves.
// ============================================================================
__global__ __launch_bounds__(256) void k_kv(const float* __restrict__ Kn,
        const u16* __restrict__ pPh, const u16* __restrict__ pPl,
        const float* __restrict__ mask, const u16* __restrict__ VT,
        float* __restrict__ KVpart, float* __restrict__ Zpart){
    __shared__ u16 phiT[256][72];     // [m][s], pad 72
    __shared__ u16 Vs[64][72];        // [d][s]
    __shared__ float zbuf[4][256];
    const int chunk = blockIdx.x, bh = blockIdx.y;
    const int b = bh>>4, h = bh&15;
    const int tid = threadIdx.x, wv = tid>>6, l = tid&63, g = l>>4, c = l&15;
    f32x4 kv[4][4];
    #pragma unroll
    for(int mt=0;mt<4;++mt) for(int dt=0;dt<4;++dt) kv[mt][dt] = f32x4{0.f,0.f,0.f,0.f};
    float zacc[16];
    #pragma unroll
    for(int nt=0;nt<16;++nt) zacc[nt]=0.f;
    const int vd = tid>>2, vs = (tid&3)*16;
    for(int t=0;t<4;++t){
        const int s0 = chunk*256 + t*64;
        __syncthreads();                       // protect prev-iter LDS reads
        { // stage V tile [64 d][64 s]
            const u16* pv = VT + ((size_t)bh*64 + vd)*4096 + s0 + vs;
            uint4 v0 = *(const uint4*)pv, v1 = *(const uint4*)(pv+8);
            *(uint4*)&Vs[vd][vs] = v0; *(uint4*)&Vs[vd][vs+8] = v1;
        }
        // phase A: u = Kn_head @ proj  (wave w -> s rows 16w..16w+15)
        f32x4 ph[16];
        #pragma unroll
        for(int nt=0;nt<16;++nt) ph[nt] = f32x4{0.f,0.f,0.f,0.f};
        #pragma unroll
        for(int ks=0;ks<2;++ks){
            const int srow = s0 + 16*wv + c;
            const float* ap = Kn + (size_t)(b*4096+srow)*1024 + h*64 + 32*ks + 8*g;
            float4 x0 = *(const float4*)ap, x1 = *(const float4*)(ap+4);
            float xv[8] = {x0.x,x0.y,x0.z,x0.w,x1.x,x1.y,x1.z,x1.w};
            bf16x8 ah, al;
            #pragma unroll
            for(int e=0;e<8;++e){ u16 hh=f2bf(xv[e]); ah[e]=(short)hh; al[e]=(short)f2bf(xv[e]-bf2f(hh)); }
            #pragma unroll
            for(int nt=0;nt<16;++nt){
                bf16x8 bh8 = *(const bf16x8*)(pPh + ((size_t)(nt*2+ks)*64 + l)*8);
                bf16x8 bl8 = *(const bf16x8*)(pPl + ((size_t)(nt*2+ks)*64 + l)*8);
                ph[nt] = MFMA(ah, bh8, ph[nt]);
                ph[nt] = MFMA(ah, bl8, ph[nt]);
                ph[nt] = MFMA(al, bh8, ph[nt]);
            }
        }
        float mk[4];
        #pragma unroll
        for(int r=0;r<4;++r) mk[r] = mask[b*4096 + s0 + 16*wv + 4*g + r];
        #pragma unroll
        for(int nt=0;nt<16;++nt){
            float zs = 0.f;
            #pragma unroll
            for(int r=0;r<4;++r){
                float phv = expf(ph[nt][r]-0.5f)*0.0625f*mk[r];
                phiT[c+16*nt][16*wv+4*g+r] = f2bf(phv);
                zs += phv;
            }
            zacc[nt] += zs;
        }
        __syncthreads();
        // phase B: KV += phiT(A, rows m) x Vs(B, cols d)
        #pragma unroll
        for(int ks=0;ks<2;++ks){
            bf16x8 afr[4], bfr[4];
            #pragma unroll
            for(int mt=0;mt<4;++mt) afr[mt] = *(const bf16x8*)&phiT[64*wv+16*mt+c][32*ks+8*g];
            #pragma unroll
            for(int dt=0;dt<4;++dt) bfr[dt] = *(const bf16x8*)&Vs[16*dt+c][32*ks+8*g];
            #pragma unroll
            for(int mt=0;mt<4;++mt)
                #pragma unroll
                for(int dt=0;dt<4;++dt)
                    kv[mt][dt] = MFMA(afr[mt], bfr[dt], kv[mt][dt]);
        }
    }
    // Z partial
    #pragma unroll
    for(int nt=0;nt<16;++nt){
        float z = zacc[nt];
        z += __shfl_xor(z,16); z += __shfl_xor(z,32);
        if (g==0) zbuf[wv][c+16*nt] = z;
    }
    __syncthreads();
    {
        float z = zbuf[0][tid]+zbuf[1][tid]+zbuf[2][tid]+zbuf[3][tid];
        Zpart[((size_t)bh*16+chunk)*256 + tid] = z;
    }
    float* kout = KVpart + ((size_t)bh*16+chunk)*16384;   // [256 m][64 d]
    #pragma unroll
    for(int mt=0;mt<4;++mt)
        #pragma unroll
        for(int dt=0;dt<4;++dt)
            #pragma unroll
            for(int r=0;r<4;++r)
                kout[(64*wv+16*mt+4*g+r)*64 + 16*dt + c] = kv[mt][dt][r];
}

// ============================================================================
// k_kvreduce (parallel): 512 blocks x 256 threads, one float4 of KV per thread.
// ============================================================================
__global__ __launch_bounds__(256) void k_kvreduce(const float* __restrict__ KVpart,
        const float* __restrict__ Zpart, u16* __restrict__ KVT, float* __restrict__ Z){
    const int gid = blockIdx.x*256 + threadIdx.x;      // 0..131071
    const int bh = gid >> 12;                          // 4096 float4 per bh
    const int i0 = (gid & 4095) * 4;                   // element idx in [256m][64d]
    float4 s = {0.f,0.f,0.f,0.f};
    const float* base = KVpart + (size_t)bh*16*16384 + i0;
    #pragma unroll
    for(int ch=0; ch<16; ++ch){
        float4 v = *(const float4*)(base + (size_t)ch*16384);
        s.x+=v.x; s.y+=v.y; s.z+=v.z; s.w+=v.w;
    }
    const int m = i0 >> 6, d = i0 & 63;                // 4 consecutive d, same m
    u16* dst = KVT + ((size_t)bh*64 + d)*256 + m;
    dst[0]   = f2bf(s.x);
    dst[256] = f2bf(s.y);
    dst[512] = f2bf(s.z);
    dst[768] = f2bf(s.w);
    if (gid < 8192){
        const int zbh = gid >> 8, zm = gid & 255;
        float z = 0.f;
        #pragma unroll
        for(int ch=0; ch<16; ++ch) z += Zpart[((size_t)zbh*16+ch)*256 + zm];
        Z[zbh*256 + zm] = z;
    }
}

// ============================================================================
// k_attn: per (s-tile 64, b*16+h): phiQ on the fly, den via shfl, num via MFMA,
// attn = 8*num/den -> bf16 [B*S][1024]. grid (64, 32), 4 waves.
// ============================================================================
__global__ __launch_bounds__(256) void k_attn(const float* __restrict__ Qn,
        const u16* __restrict__ pPh, const u16* __restrict__ pPl,
        const u16* __restrict__ KVT, const float* __restrict__ Z, u16* __restrict__ attn){
    __shared__ u16 phi[64][264];      // [s][m], pad 264
    __shared__ float Zs[256];
    const int st = blockIdx.x, bh = blockIdx.y;
    const int b = bh>>4, h = bh&15;
    const int tid = threadIdx.x, wv = tid>>6, l = tid&63, g = l>>4, c = l&15;
    Zs[tid] = Z[bh*256 + tid];
    const int s0 = st*64;
    f32x4 ph[16];
    #pragma unroll
    for(int nt=0;nt<16;++nt) ph[nt] = f32x4{0.f,0.f,0.f,0.f};
    #pragma unroll
    for(int ks=0;ks<2;++ks){
        const int srow = s0 + 16*wv + c;
        const float* ap = Qn + (size_t)(b*4096+srow)*1024 + h*64 + 32*ks + 8*g;
        float4 x0 = *(const float4*)ap, x1 = *(const float4*)(ap+4);
        float xv[8] = {x0.x,x0.y,x0.z,x0.w,x1.x,x1.y,x1.z,x1.w};
        bf16x8 ah, al;
        #pragma unroll
        for(int e=0;e<8;++e){ u16 hh=f2bf(xv[e]); ah[e]=(short)hh; al[e]=(short)f2bf(xv[e]-bf2f(hh)); }
        #pragma unroll
        for(int nt=0;nt<16;++nt){
            bf16x8 bh8 = *(const bf16x8*)(pPh + ((size_t)(nt*2+ks)*64 + l)*8);
            bf16x8 bl8 = *(const bf16x8*)(pPl + ((size_t)(nt*2+ks)*64 + l)*8);
            ph[nt] = MFMA(ah, bh8, ph[nt]);
            ph[nt] = MFMA(ah, bl8, ph[nt]);
            ph[nt] = MFMA(al, bh8, ph[nt]);
        }
    }
    __syncthreads();                  // Zs visible
    float den[4] = {0.f,0.f,0.f,0.f};
    #pragma unroll
    for(int nt=0;nt<16;++nt){
        float zv = Zs[c+16*nt];
        #pragma unroll
        for(int r=0;r<4;++r){
            float phv = expf(ph[nt][r]-0.5f)*0.0625f;
            den[r] += phv*zv;
            phi[16*wv+4*g+r][c+16*nt] = f2bf(phv);
        }
    }
    #pragma unroll
    for(int r=0;r<4;++r){
        den[r] += __shfl_xor(den[r],1); den[r] += __shfl_xor(den[r],2);
        den[r] += __shfl_xor(den[r],4); den[r] += __shfl_xor(den[r],8);
        den[r] += 1e-6f;
    }
    __syncthreads();                  // phi written
    f32x4 nm[4];
    #pragma unroll
    for(int dt=0;dt<4;++dt) nm[dt] = f32x4{0.f,0.f,0.f,0.f};
    #pragma unroll
    for(int j=0;j<8;++j){
        bf16x8 af = *(const bf16x8*)&phi[16*wv+c][32*j+8*g];
        #pragma unroll
        for(int dt=0;dt<4;++dt){
            bf16x8 bfr = *(const bf16x8*)(KVT + ((size_t)bh*64 + 16*dt + c)*256 + 32*j + 8*g);
            nm[dt] = MFMA(af, bfr, nm[dt]);
        }
    }
    #pragma unroll
    for(int dt=0;dt<4;++dt)
        #pragma unroll
        for(int r=0;r<4;++r){
            const int srow = s0 + 16*wv + 4*g + r;
            attn[(size_t)(b*4096+srow)*1024 + h*64 + 16*dt + c] = f2bf(nm[dt][r]*8.f/den[r]);
        }
}

// ============================================================================
// k_out: out = attn(bf16) @ WfT(bf16) + bf, fp32 out. BM=128 BN=256 BK=64,
// 3 LDS slots, stage 2 tiles ahead, ONE vmcnt(6)+barrier per tile.
// 8 waves (2M x 4N), per-wave 64x64, acc[4][4]. grid (64,4) = 256 = 1 round.
// Units/tile: B0..B3 (256 rows), A0,A1 (128 rows) — all needed at tile entry,
// staged 2 tiles ahead so certify-gap >= 2 tiles >> HBM latency.
// ============================================================================
__global__ __launch_bounds__(512,2) void k_out(const u16* __restrict__ attn,
        const u16* __restrict__ Wh, const float* __restrict__ bfb, float* __restrict__ out){
    __shared__ u16 As[3*128*64];   // 48KB
    __shared__ u16 Bs[3*256*64];   // 96KB
    const int bx = blockIdx.x, by = blockIdx.y;
    const int tid = threadIdx.x, w = tid>>6, l = tid&63, g = l>>4, c = l&15;
    const int wr = w>>2, wc = w&3;
    const u16* Ap = attn + (size_t)bx*128*1024;
    const u16* Bp = Wh + (size_t)by*256*1024;
    const int srow_ = w*8 + (l>>3);
    const int scol_ = ((l&7) ^ (l>>3))*8;
#define SA(slot,j,k0) GLOAD16(&As[(slot)*(128*64) + ((j)*64 + w*8)*64], Ap + (size_t)((j)*64 + srow_)*1024 + (k0) + scol_)
#define SB(slot,j,k0) GLOAD16(&Bs[(slot)*(256*64) + ((j)*64 + w*8)*64], Bp + (size_t)((j)*64 + srow_)*1024 + (k0) + scol_)
    f32x4 acc[4][4];
    #pragma unroll
    for(int mt=0;mt<4;++mt)
        #pragma unroll
        for(int nt=0;nt<4;++nt) acc[mt][nt] = f32x4{0.f,0.f,0.f,0.f};
    // prologue: tile0 -> slot0, tile1 -> slot1 (6 units each)
    SB(0,0,0); SB(0,1,0); SB(0,2,0); SB(0,3,0); SA(0,0,0); SA(0,1,0);
    SB(1,0,64); SB(1,1,64); SB(1,2,64); SB(1,3,64); SA(1,0,64); SA(1,1,64);
    asm volatile("s_waitcnt vmcnt(6)" ::: "memory");
    __builtin_amdgcn_s_barrier();
    __builtin_amdgcn_sched_barrier(0);
    for(int kt=0; kt<16; ++kt){
        const int sl = kt%3, st2 = (kt+2)%3, k2 = (kt+2)*64;
        const bool more = kt <= 13;
        const u16* Asl = As + sl*(128*64);
        const u16* Bsl = Bs + sl*(256*64);
        bf16x8 bf_[4][2];
        #pragma unroll
        for(int nt=0;nt<4;++nt)
            #pragma unroll
            for(int ks=0;ks<2;++ks)
                bf_[nt][ks] = *(const bf16x8*)&Bsl[swz(64*wc+16*nt+c, 4*ks+g)];
        if(more){ SB(st2,0,k2); SB(st2,1,k2); SA(st2,0,k2); }
        __builtin_amdgcn_s_setprio(1);
        #pragma unroll
        for(int mt=0;mt<2;++mt){
            bf16x8 a0 = *(const bf16x8*)&Asl[swz(64*wr+16*mt+c, g)];
            bf16x8 a1 = *(const bf16x8*)&Asl[swz(64*wr+16*mt+c, 4+g)];
            #pragma unroll
            for(int nt=0;nt<4;++nt){
                acc[mt][nt] = MFMA(a0, bf_[nt][0], acc[mt][nt]);
                acc[mt][nt] = MFMA(a1, bf_[nt][1], acc[mt][nt]);
            }
        }
        __builtin_amdgcn_s_setprio(0);
        if(more){ SB(st2,2,k2); SB(st2,3,k2); SA(st2,1,k2); }
        __builtin_amdgcn_s_setprio(1);
        #pragma unroll
        for(int mt=2;mt<4;++mt){
            bf16x8 a0 = *(const bf16x8*)&Asl[swz(64*wr+16*mt+c, g)];
            bf16x8 a1 = *(const bf16x8*)&Asl[swz(64*wr+16*mt+c, 4+g)];
            #pragma unroll
            for(int nt=0;nt<4;++nt){
                acc[mt][nt] = MFMA(a0, bf_[nt][0], acc[mt][nt]);
                acc[mt][nt] = MFMA(a1, bf_[nt][1], acc[mt][nt]);
            }
        }
        __builtin_amdgcn_s_setprio(0);
        if(more)           asm volatile("s_waitcnt vmcnt(6)" ::: "memory");
        else if(kt == 14)  asm volatile("s_waitcnt vmcnt(0)" ::: "memory");
        __builtin_amdgcn_s_barrier();
        __builtin_amdgcn_sched_barrier(0);
    }
#undef SA
#undef SB
    const int n0 = by*256 + 64*wc;
    #pragma unroll
    for(int mt=0;mt<4;++mt){
        const int rowb = bx*128 + 64*wr + 16*mt + 4*g;
        #pragma unroll
        for(int nt=0;nt<4;++nt){
            const float bb = bfb[n0+16*nt+c];
            #pragma unroll
            for(int r=0;r<4;++r)
                out[(size_t)(rowb+r)*1024 + n0 + 16*nt + c] = acc[mt][nt][r] + bb;
        }
    }
}

// ============================================================================
extern "C" void kernel_launch(void* const* d_in, const int* in_sizes, int n_in,
                              void* d_out, int out_size, void* d_ws, size_t ws_size,
                              hipStream_t stream){
    (void)in_sizes; (void)n_in; (void)out_size;
    const float* X    = (const float*)d_in[0];
    const float* mask = (const float*)d_in[1];
    const float* Wq   = (const float*)d_in[2];
    const float* bq   = (const float*)d_in[3];
    const float* Wk   = (const float*)d_in[4];
    const float* bk   = (const float*)d_in[5];
    const float* Wv   = (const float*)d_in[6];
    const float* bv   = (const float*)d_in[7];
    const float* Wf   = (const float*)d_in[8];
    const float* bfb  = (const float*)d_in[9];
    const float* proj = (const float*)d_in[10];
    float* out = (float*)d_out;

    char* w = (char*)d_ws;
    size_t off = 0;
    auto alloc = [&](size_t n)->void*{ void* p = w + off; off = (off + n + 255) & ~(size_t)255; return p; };
    u16*   Xb     = (u16*)  alloc((size_t)8192*1024*2);    // X bf16
    u16*   WT     = (u16*)  alloc((size_t)3*1048576*2);    // Wq,Wk,Wv transposed [n][k]
    u16*   Wfh    = (u16*)  alloc((size_t)1048576*2);      // WfT hi
    u16*   pPh    = (u16*)  alloc(16384*2);                // proj packed hi
    u16*   pPl    = (u16*)  alloc(16384*2);                // proj packed lo
    float* Qn     = (float*)alloc((size_t)8192*1024*4);    // normalized Q fp32
    float* Kn     = (float*)alloc((size_t)8192*1024*4);    // normalized K fp32
    u16*   VT     = (u16*)  alloc((size_t)32*64*4096*2);   // V^T per head bf16
    float* KVpart = (float*)alloc((size_t)32*16*16384*4);  // split-K KV partials
    float* Zpart  = (float*)alloc((size_t)32*16*256*4);
    u16*   KVT    = (u16*)  alloc((size_t)32*64*256*2);    // KV^T [d][m] bf16
    float* Zr     = (float*)alloc((size_t)32*256*4);
    u16*   attnB  = (u16*)  alloc((size_t)8192*1024*2);    // attn bf16
    if (off > ws_size) return;  // ws too small: fail cleanly (output stays zero)

    k_transpose<<<dim3(32,32), 256, 0, stream>>>(Wq, WT,           (u16*)nullptr, 1024, 1024);
    k_transpose<<<dim3(32,32), 256, 0, stream>>>(Wk, WT+1048576,   (u16*)nullptr, 1024, 1024);
    k_transpose<<<dim3(32,32), 256, 0, stream>>>(Wv, WT+2097152,   (u16*)nullptr, 1024, 1024);
    k_transpose<<<dim3(32,32), 256, 0, stream>>>(Wf, Wfh,          (u16*)nullptr, 1024, 1024);
    k_pack_proj<<<dim3(64), 256, 0, stream>>>(proj, pPh, pPl);
    k_convertX<<<dim3(8192), 256, 0, stream>>>(X, Xb);
    k_qkv<<<dim3(32,12), 512, 0, stream>>>(Xb, WT, bq, bk, bv, Qn, Kn, VT);
    k_kv<<<dim3(16,32), 256, 0, stream>>>(Kn, pPh, pPl, mask, VT, KVpart, Zpart);
    k_kvreduce<<<dim3(512), 256, 0, stream>>>(KVpart, Zpart, KVT, Zr);
    k_attn<<<dim3(64,32), 256, 0, stream>>>(Qn, pPh, pPl, KVT, Zr, attnB);
    k_out<<<dim3(64,4), 512, 0, stream>>>(attnB, Wfh, bfb, out);
}

// Round 10
// 235.481 us; speedup vs baseline: 1.1219x; 1.1219x over previous
//
#include <hip/hip_runtime.h>
#include <cmath>

typedef unsigned short u16;
typedef unsigned int   u32;
typedef __attribute__((ext_vector_type(8))) short bf16x8;  // 8 bf16 in 4 VGPRs
typedef __attribute__((ext_vector_type(4))) float f32x4;   // MFMA accumulator

#define DEV __device__ __forceinline__
#define MFMA(a,b,c) __builtin_amdgcn_mfma_f32_16x16x32_bf16((a),(b),(c),0,0,0)

// async global->LDS, 16B per lane: lane l writes dst + l*16 bytes (dst wave-uniform)
#define GLOAD16(dst, src) __builtin_amdgcn_global_load_lds( \
    (const __attribute__((address_space(1))) void*)(src), \
    (__attribute__((address_space(3))) void*)(dst), 16, 0, 0)

// ---- bf16 helpers (RNE) ----
DEV u16 f2bf(float x){ union{float f;u32 u;} v; v.f=x; u32 r=v.u+0x7FFFu+((v.u>>16)&1u); return (u16)(r>>16); }
DEV float bf2f(u16 h){ union{u32 u;float f;} v; v.u=((u32)h)<<16; return v.f; }

// LDS read-side swizzle: within a row (64 elems = 8 col-blocks of 8), XOR the
// col-block with row&7. Same involution on the gload SOURCE col, LDS dest
// linear (rule #21). HW-verified rounds 7-9: conflicts=0, absmax unchanged.
DEV int swz(int row, int cb){ return row*64 + ((cb ^ (row&7))*8); }

// stage one 64x64 unit: 512 threads x 16B; dst linear, src col inverse-swizzled
#define STGU(arr, slotsz, slot, j, P, k0) GLOAD16( \
    &(arr)[(slot)*(slotsz) + ((j)*64 + w*8)*64], \
    (P) + (size_t)((j)*64 + srow_)*1024 + (k0) + scol_)

// ============================================================================
// GEMM core (round-8 proven, 72us): BM=128 x BN=256, BK=64, K=1024 (16 tiles),
// 512 thr = 8 waves (2M x 4N). 3 LDS slots, stage 2 tiles ahead (6 gloads/tile),
// vmcnt(6) once per tile. 2 phases/tile x 16 MFMA. acc[4][4] per wave.
// ============================================================================
#define GEMM_CORE_128x256(As, Bs, Ap, Bp, acc) do{ \
    const int srow_ = w*8 + (l>>3); \
    const int scol_ = ((l&7) ^ (l>>3))*8; \
    STGU(Bs,256*64,0,0,Bp,0); STGU(Bs,256*64,0,1,Bp,0); STGU(Bs,256*64,0,2,Bp,0); \
    STGU(Bs,256*64,0,3,Bp,0); STGU(As,128*64,0,0,Ap,0); STGU(As,128*64,0,1,Ap,0); \
    STGU(Bs,256*64,1,0,Bp,64); STGU(Bs,256*64,1,1,Bp,64); STGU(Bs,256*64,1,2,Bp,64); \
    STGU(Bs,256*64,1,3,Bp,64); STGU(As,128*64,1,0,Ap,64); STGU(As,128*64,1,1,Ap,64); \
    asm volatile("s_waitcnt vmcnt(6)" ::: "memory"); \
    __builtin_amdgcn_s_barrier(); \
    __builtin_amdgcn_sched_barrier(0); \
    for(int kt=0; kt<16; ++kt){ \
        const int sl = kt % 3; \
        const int st = (kt+2) % 3; \
        const int k2 = (kt+2)*64; \
        const u16* Asl = (As) + sl*(128*64); \
        const u16* Bsl = (Bs) + sl*(256*64); \
        bf16x8 bf_[4][2], af_[2][2]; \
        /* ---- phase 0 ---- */ \
        _Pragma("unroll") \
        for(int nt=0;nt<4;++nt) \
            _Pragma("unroll") \
            for(int ks=0;ks<2;++ks) \
                bf_[nt][ks] = *(const bf16x8*)&Bsl[swz(64*wc+16*nt+c, 4*ks+g)]; \
        _Pragma("unroll") \
        for(int i=0;i<2;++i) \
            _Pragma("unroll") \
            for(int ks=0;ks<2;++ks) \
                af_[i][ks] = *(const bf16x8*)&Asl[swz(64*wr+16*i+c, 4*ks+g)]; \
        if (kt<=13){ STGU(Bs,256*64,st,0,Bp,k2); STGU(Bs,256*64,st,1,Bp,k2); STGU(Bs,256*64,st,2,Bp,k2); } \
        __builtin_amdgcn_s_barrier(); \
        asm volatile("s_waitcnt lgkmcnt(0)" ::: "memory"); \
        __builtin_amdgcn_sched_barrier(0); \
        __builtin_amdgcn_s_setprio(1); \
        _Pragma("unroll") \
        for(int i=0;i<2;++i) \
            _Pragma("unroll") \
            for(int nt=0;nt<4;++nt) \
                _Pragma("unroll") \
                for(int ks=0;ks<2;++ks) \
                    acc[i][nt] = MFMA(af_[i][ks], bf_[nt][ks], acc[i][nt]); \
        __builtin_amdgcn_s_setprio(0); \
        __builtin_amdgcn_s_barrier(); \
        __builtin_amdgcn_sched_barrier(0); \
        /* ---- phase 1 ---- */ \
        _Pragma("unroll") \
        for(int i=0;i<2;++i) \
            _Pragma("unroll") \
            for(int ks=0;ks<2;++ks) \
                af_[i][ks] = *(const bf16x8*)&Asl[swz(64*wr+16*(2+i)+c, 4*ks+g)]; \
        if (kt<=13){ STGU(Bs,256*64,st,3,Bp,k2); STGU(As,128*64,st,0,Ap,k2); STGU(As,128*64,st,1,Ap,k2); } \
        __builtin_amdgcn_s_barrier(); \
        asm volatile("s_waitcnt lgkmcnt(0)" ::: "memory"); \
        __builtin_amdgcn_sched_barrier(0); \
        __builtin_amdgcn_s_setprio(1); \
        _Pragma("unroll") \
        for(int i=0;i<2;++i) \
            _Pragma("unroll") \
            for(int nt=0;nt<4;++nt) \
                _Pragma("unroll") \
                for(int ks=0;ks<2;++ks) \
                    acc[2+i][nt] = MFMA(af_[i][ks], bf_[nt][ks], acc[2+i][nt]); \
        __builtin_amdgcn_s_setprio(0); \
        if (kt<=13)      { asm volatile("s_waitcnt vmcnt(6)" ::: "memory"); } \
        else if (kt==14) { asm volatile("s_waitcnt vmcnt(0)" ::: "memory"); } \
        __builtin_amdgcn_s_barrier(); \
        __builtin_amdgcn_sched_barrier(0); \
    } \
}while(0)

// ============================================================================
// prep kernels
// ============================================================================

// in fp32 [R][C] -> hi bf16 [C][R] (+ optional lo = bf16(x - hi))
__global__ __launch_bounds__(256) void k_transpose(const float* __restrict__ in,
        u16* __restrict__ hi, u16* __restrict__ lo, int R, int C){
    __shared__ float t[32][33];
    const int r0 = blockIdx.y*32, c0 = blockIdx.x*32;
    const int lr = threadIdx.x>>3, lc = (threadIdx.x&7)*4;
    float4 v = *(const float4*)(in + (size_t)(r0+lr)*C + c0 + lc);
    t[lr][lc]=v.x; t[lr][lc+1]=v.y; t[lr][lc+2]=v.z; t[lr][lc+3]=v.w;
    __syncthreads();
    float vals[4]; u16 h[4];
    #pragma unroll
    for(int j=0;j<4;++j){ vals[j]=t[lc+j][lr]; h[j]=f2bf(vals[j]); }
    ushort4 o; o.x=h[0]; o.y=h[1]; o.z=h[2]; o.w=h[3];
    *(ushort4*)(hi + (size_t)(c0+lr)*R + r0+lc) = o;
    if (lo){
        ushort4 q; q.x=f2bf(vals[0]-bf2f(h[0])); q.y=f2bf(vals[1]-bf2f(h[1]));
        q.z=f2bf(vals[2]-bf2f(h[2])); q.w=f2bf(vals[3]-bf2f(h[3]));
        *(ushort4*)(lo + (size_t)(c0+lr)*R + r0+lc) = q;
    }
}

// proj [64 d][256 m] fp32 -> packed B-fragments (hi only used now):
// pPh[((nt*2+ks)*64 + lane)*8 + e] = bf16(proj[32*ks+8*(lane/16)+e][16*nt+lane%16])
__global__ __launch_bounds__(256) void k_pack_proj(const float* __restrict__ proj,
        u16* __restrict__ ph){
    int idx = blockIdx.x*256 + threadIdx.x;       // 0..16383
    int e = idx&7, l = (idx>>3)&63, f = idx>>9;   // f = nt*2+ks
    int nt = f>>1, ks = f&1;
    int d = 32*ks + 8*(l>>4) + e;
    int m = 16*nt + (l&15);
    ph[idx] = f2bf(proj[d*256 + m]);
}

__global__ __launch_bounds__(256) void k_convertX(const float* __restrict__ X, u16* __restrict__ Xb){
    size_t i = ((size_t)blockIdx.x*256 + threadIdx.x)*4;
    float4 v = *(const float4*)(X+i);
    ushort4 o; o.x=f2bf(v.x); o.y=f2bf(v.y); o.z=f2bf(v.z); o.w=f2bf(v.w);
    *(ushort4*)(Xb+i) = o;
}

// ============================================================================
// k_qkv: C = X @ {Wq,Wk,Wv}; round-8 GEMM core (BM=128/BN=256/BK=64, 3-slot).
// wsel<2: +bias, per-head L2-normalize, store BF16 Qb/Kb [B*S][1024].
// wsel==2: +bias, store bf16 V transposed per head: VT[(b*16+h)*64+d][4096].
// grid (64, 12) = 768 = 3 exact CU rounds: y/4 = wsel, y%4 = 256-col blk.
// ============================================================================
__global__ __launch_bounds__(512,2) void k_qkv(const u16* __restrict__ Xb, const u16* __restrict__ WT,
        const float* __restrict__ bq, const float* __restrict__ bk, const float* __restrict__ bv,
        u16* __restrict__ Qb, u16* __restrict__ Kb, u16* __restrict__ VT){
    __shared__ u16 As[3*128*64];   // 48KB
    __shared__ u16 Bs[3*256*64];   // 96KB
    const int bx = blockIdx.x, y = blockIdx.y;
    const int wsel = y>>2, nb = y&3;
    const int tid = threadIdx.x, w = tid>>6, l = tid&63, g = l>>4, c = l&15;
    const int wr = w>>2, wc = w&3;
    const u16* Ap = Xb + (size_t)bx*128*1024;
    const u16* Bp = WT + (size_t)wsel*1048576 + (size_t)nb*256*1024;
    f32x4 acc[4][4];
    #pragma unroll
    for(int mt=0;mt<4;++mt)
        #pragma unroll
        for(int nt=0;nt<4;++nt) acc[mt][nt] = f32x4{0.f,0.f,0.f,0.f};

    GEMM_CORE_128x256(As, Bs, Ap, Bp, acc);

    const int n0 = nb*256 + 64*wc;    // col within this wsel's 1024
    const int b = bx>>5;
    if (wsel < 2){
        u16* Out = wsel ? Kb : Qb;
        const float* bias = wsel ? bk : bq;
        float bb[4];
        #pragma unroll
        for(int nt=0;nt<4;++nt) bb[nt] = bias[n0+16*nt+c];
        #pragma unroll
        for(int mt=0;mt<4;++mt){
            #pragma unroll
            for(int nt=0;nt<4;++nt)
                #pragma unroll
                for(int r=0;r<4;++r) acc[mt][nt][r] += bb[nt];
            // wave's 64 cols are one head -> norm over nt(4) x shfl16
            #pragma unroll
            for(int r=0;r<4;++r){
                float ss = 0.f;
                #pragma unroll
                for(int nt=0;nt<4;++nt){ float vv = acc[mt][nt][r]; ss += vv*vv; }
                ss += __shfl_xor(ss,1); ss += __shfl_xor(ss,2);
                ss += __shfl_xor(ss,4); ss += __shfl_xor(ss,8);
                float sc = 1.f/(sqrtf(ss)+1e-6f);
                #pragma unroll
                for(int nt=0;nt<4;++nt) acc[mt][nt][r] *= sc;
            }
            const int rowb = bx*128 + 64*wr + 16*mt + 4*g;
            #pragma unroll
            for(int nt=0;nt<4;++nt)
                #pragma unroll
                for(int r=0;r<4;++r)
                    Out[(size_t)(rowb+r)*1024 + n0 + 16*nt + c] = f2bf(acc[mt][nt][r]);
        }
    } else {
        const int h = nb*4 + wc;
        float bb[4];
        #pragma unroll
        for(int nt=0;nt<4;++nt) bb[nt] = bv[n0+16*nt+c];
        #pragma unroll
        for(int mt=0;mt<4;++mt)
            #pragma unroll
            for(int nt=0;nt<4;++nt){
                const int d = 16*nt + c;
                const int s0m = (bx&31)*128 + 64*wr + 16*mt + 4*g;
                ushort4 o;
                o.x = f2bf(acc[mt][nt][0]+bb[nt]); o.y = f2bf(acc[mt][nt][1]+bb[nt]);
                o.z = f2bf(acc[mt][nt][2]+bb[nt]); o.w = f2bf(acc[mt][nt][3]+bb[nt]);
                *(ushort4*)(VT + ((size_t)(b*16+h)*64 + d)*4096 + s0m) = o;
            }
    }
}

// ============================================================================
// k_kv: per (chunk, b*16+h): KV[m,d] = sum_s phiK[s,m] V[s,d]; Z[m] = sum_s phiK
// phiK: single-pass bf16 MFMA (Kb bf16 x pPh bf16). Split-K 16 chunks of 256 s.
// grid (16, 32), 4 waves.
// ============================================================================
__global__ __launch_bounds__(256) void k_kv(const u16* __restrict__ Kb,
        const u16* __restrict__ pPh,
        const float* __restrict__ mask, const u16* __restrict__ VT,
        float* __restrict__ KVpart, float* __restrict__ Zpart){
    __shared__ u16 phiT[256][72];     // [m][s], pad 72
    __shared__ u16 Vs[64][72];        // [d][s]
    __shared__ float zbuf[4][256];
    const int chunk = blockIdx.x, bh = blockIdx.y;
    const int b = bh>>4, h = bh&15;
    const int tid = threadIdx.x, wv = tid>>6, l = tid&63, g = l>>4, c = l&15;
    f32x4 kv[4][4];
    #pragma unroll
    for(int mt=0;mt<4;++mt) for(int dt=0;dt<4;++dt) kv[mt][dt] = f32x4{0.f,0.f,0.f,0.f};
    float zacc[16];
    #pragma unroll
    for(int nt=0;nt<16;++nt) zacc[nt]=0.f;
    const int vd = tid>>2, vs = (tid&3)*16;
    for(int t=0;t<4;++t){
        const int s0 = chunk*256 + t*64;
        __syncthreads();                       // protect prev-iter LDS reads
        { // stage V tile [64 d][64 s]
            const u16* pv = VT + ((size_t)bh*64 + vd)*4096 + s0 + vs;
            uint4 v0 = *(const uint4*)pv, v1 = *(const uint4*)(pv+8);
            *(uint4*)&Vs[vd][vs] = v0; *(uint4*)&Vs[vd][vs+8] = v1;
        }
        // phase A: u = K_head @ proj  (wave w -> s rows 16w..16w+15), single pass
        f32x4 ph[16];
        #pragma unroll
        for(int nt=0;nt<16;++nt) ph[nt] = f32x4{0.f,0.f,0.f,0.f};
        #pragma unroll
        for(int ks=0;ks<2;++ks){
            const int srow = s0 + 16*wv + c;
            bf16x8 ah = *(const bf16x8*)(Kb + (size_t)(b*4096+srow)*1024 + h*64 + 32*ks + 8*g);
            #pragma unroll
            for(int nt=0;nt<16;++nt){
                bf16x8 bh8 = *(const bf16x8*)(pPh + ((size_t)(nt*2+ks)*64 + l)*8);
                ph[nt] = MFMA(ah, bh8, ph[nt]);
            }
        }
        float mk[4];
        #pragma unroll
        for(int r=0;r<4;++r) mk[r] = mask[b*4096 + s0 + 16*wv + 4*g + r];
        #pragma unroll
        for(int nt=0;nt<16;++nt){
            float zs = 0.f;
            #pragma unroll
            for(int r=0;r<4;++r){
                float phv = expf(ph[nt][r]-0.5f)*0.0625f*mk[r];
                phiT[c+16*nt][16*wv+4*g+r] = f2bf(phv);
                zs += phv;
            }
            zacc[nt] += zs;
        }
        __syncthreads();
        // phase B: KV += phiT(A, rows m) x Vs(B, cols d)
        #pragma unroll
        for(int ks=0;ks<2;++ks){
            bf16x8 afr[4], bfr[4];
            #pragma unroll
            for(int mt=0;mt<4;++mt) afr[mt] = *(const bf16x8*)&phiT[64*wv+16*mt+c][32*ks+8*g];
            #pragma unroll
            for(int dt=0;dt<4;++dt) bfr[dt] = *(const bf16x8*)&Vs[16*dt+c][32*ks+8*g];
            #pragma unroll
            for(int mt=0;mt<4;++mt)
                #pragma unroll
                for(int dt=0;dt<4;++dt)
                    kv[mt][dt] = MFMA(afr[mt], bfr[dt], kv[mt][dt]);
        }
    }
    // Z partial
    #pragma unroll
    for(int nt=0;nt<16;++nt){
        float z = zacc[nt];
        z += __shfl_xor(z,16); z += __shfl_xor(z,32);
        if (g==0) zbuf[wv][c+16*nt] = z;
    }
    __syncthreads();
    {
        float z = zbuf[0][tid]+zbuf[1][tid]+zbuf[2][tid]+zbuf[3][tid];
        Zpart[((size_t)bh*16+chunk)*256 + tid] = z;
    }
    float* kout = KVpart + ((size_t)bh*16+chunk)*16384;   // [256 m][64 d]
    #pragma unroll
    for(int mt=0;mt<4;++mt)
        #pragma unroll
        for(int dt=0;dt<4;++dt)
            #pragma unroll
            for(int r=0;r<4;++r)
                kout[(64*wv+16*mt+4*g+r)*64 + 16*dt + c] = kv[mt][dt][r];
}

// ============================================================================
// k_kvreduce (parallel): 512 blocks x 256 threads, one float4 of KV per thread.
// ============================================================================
__global__ __launch_bounds__(256) void k_kvreduce(const float* __restrict__ KVpart,
        const float* __restrict__ Zpart, u16* __restrict__ KVT, float* __restrict__ Z){
    const int gid = blockIdx.x*256 + threadIdx.x;      // 0..131071
    const int bh = gid >> 12;                          // 4096 float4 per bh
    const int i0 = (gid & 4095) * 4;                   // element idx in [256m][64d]
    float4 s = {0.f,0.f,0.f,0.f};
    const float* base = KVpart + (size_t)bh*16*16384 + i0;
    #pragma unroll
    for(int ch=0; ch<16; ++ch){
        float4 v = *(const float4*)(base + (size_t)ch*16384);
        s.x+=v.x; s.y+=v.y; s.z+=v.z; s.w+=v.w;
    }
    const int m = i0 >> 6, d = i0 & 63;                // 4 consecutive d, same m
    u16* dst = KVT + ((size_t)bh*64 + d)*256 + m;
    dst[0]   = f2bf(s.x);
    dst[256] = f2bf(s.y);
    dst[512] = f2bf(s.z);
    dst[768] = f2bf(s.w);
    if (gid < 8192){
        const int zbh = gid >> 8, zm = gid & 255;
        float z = 0.f;
        #pragma unroll
        for(int ch=0; ch<16; ++ch) z += Zpart[((size_t)zbh*16+ch)*256 + zm];
        Z[zbh*256 + zm] = z;
    }
}

// ============================================================================
// k_attn: per (s-tile 64, b*16+h): phiQ single-pass bf16, den via shfl, num
// via MFMA, attn = 8*num/den -> bf16 [B*S][1024]. grid (64, 32), 4 waves.
// ============================================================================
__global__ __launch_bounds__(256) void k_attn(const u16* __restrict__ Qb,
        const u16* __restrict__ pPh,
        const u16* __restrict__ KVT, const float* __restrict__ Z, u16* __restrict__ attn){
    __shared__ u16 phi[64][264];      // [s][m], pad 264
    __shared__ float Zs[256];
    const int st = blockIdx.x, bh = blockIdx.y;
    const int b = bh>>4, h = bh&15;
    const int tid = threadIdx.x, wv = tid>>6, l = tid&63, g = l>>4, c = l&15;
    Zs[tid] = Z[bh*256 + tid];
    const int s0 = st*64;
    f32x4 ph[16];
    #pragma unroll
    for(int nt=0;nt<16;++nt) ph[nt] = f32x4{0.f,0.f,0.f,0.f};
    #pragma unroll
    for(int ks=0;ks<2;++ks){
        const int srow = s0 + 16*wv + c;
        bf16x8 ah = *(const bf16x8*)(Qb + (size_t)(b*4096+srow)*1024 + h*64 + 32*ks + 8*g);
        #pragma unroll
        for(int nt=0;nt<16;++nt){
            bf16x8 bh8 = *(const bf16x8*)(pPh + ((size_t)(nt*2+ks)*64 + l)*8);
            ph[nt] = MFMA(ah, bh8, ph[nt]);
        }
    }
    __syncthreads();                  // Zs visible
    float den[4] = {0.f,0.f,0.f,0.f};
    #pragma unroll
    for(int nt=0;nt<16;++nt){
        float zv = Zs[c+16*nt];
        #pragma unroll
        for(int r=0;r<4;++r){
            float phv = expf(ph[nt][r]-0.5f)*0.0625f;
            den[r] += phv*zv;
            phi[16*wv+4*g+r][c+16*nt] = f2bf(phv);
        }
    }
    #pragma unroll
    for(int r=0;r<4;++r){
        den[r] += __shfl_xor(den[r],1); den[r] += __shfl_xor(den[r],2);
        den[r] += __shfl_xor(den[r],4); den[r] += __shfl_xor(den[r],8);
        den[r] += 1e-6f;
    }
    __syncthreads();                  // phi written
    f32x4 nm[4];
    #pragma unroll
    for(int dt=0;dt<4;++dt) nm[dt] = f32x4{0.f,0.f,0.f,0.f};
    #pragma unroll
    for(int j=0;j<8;++j){
        bf16x8 af = *(const bf16x8*)&phi[16*wv+c][32*j+8*g];
        #pragma unroll
        for(int dt=0;dt<4;++dt){
            bf16x8 bfr = *(const bf16x8*)(KVT + ((size_t)bh*64 + 16*dt + c)*256 + 32*j + 8*g);
            nm[dt] = MFMA(af, bfr, nm[dt]);
        }
    }
    #pragma unroll
    for(int dt=0;dt<4;++dt)
        #pragma unroll
        for(int r=0;r<4;++r){
            const int srow = s0 + 16*wv + 4*g + r;
            attn[(size_t)(b*4096+srow)*1024 + h*64 + 16*dt + c] = f2bf(nm[dt][r]*8.f/den[r]);
        }
}

// ============================================================================
// k_out: out = attn(bf16) @ WfT(bf16) + bf, fp32 out. BM=128 BN=256 BK=64,
// 3 LDS slots, stage 2 tiles ahead, ONE vmcnt(6)+barrier per tile (round-9,
// measured neutral-positive). grid (64,4) = 256 = 1 exact round.
// ============================================================================
__global__ __launch_bounds__(512,2) void k_out(const u16* __restrict__ attn,
        const u16* __restrict__ Wh, const float* __restrict__ bfb, float* __restrict__ out){
    __shared__ u16 As[3*128*64];   // 48KB
    __shared__ u16 Bs[3*256*64];   // 96KB
    const int bx = blockIdx.x, by = blockIdx.y;
    const int tid = threadIdx.x, w = tid>>6, l = tid&63, g = l>>4, c = l&15;
    const int wr = w>>2, wc = w&3;
    const u16* Ap = attn + (size_t)bx*128*1024;
    const u16* Bp = Wh + (size_t)by*256*1024;
    const int srow_ = w*8 + (l>>3);
    const int scol_ = ((l&7) ^ (l>>3))*8;
#define SA(slot,j,k0) GLOAD16(&As[(slot)*(128*64) + ((j)*64 + w*8)*64], Ap + (size_t)((j)*64 + srow_)*1024 + (k0) + scol_)
#define SB(slot,j,k0) GLOAD16(&Bs[(slot)*(256*64) + ((j)*64 + w*8)*64], Bp + (size_t)((j)*64 + srow_)*1024 + (k0) + scol_)
    f32x4 acc[4][4];
    #pragma unroll
    for(int mt=0;mt<4;++mt)
        #pragma unroll
        for(int nt=0;nt<4;++nt) acc[mt][nt] = f32x4{0.f,0.f,0.f,0.f};
    // prologue: tile0 -> slot0, tile1 -> slot1 (6 units each)
    SB(0,0,0); SB(0,1,0); SB(0,2,0); SB(0,3,0); SA(0,0,0); SA(0,1,0);
    SB(1,0,64); SB(1,1,64); SB(1,2,64); SB(1,3,64); SA(1,0,64); SA(1,1,64);
    asm volatile("s_waitcnt vmcnt(6)" ::: "memory");
    __builtin_amdgcn_s_barrier();
    __builtin_amdgcn_sched_barrier(0);
    for(int kt=0; kt<16; ++kt){
        const int sl = kt%3, st2 = (kt+2)%3, k2 = (kt+2)*64;
        const bool more = kt <= 13;
        const u16* Asl = As + sl*(128*64);
        const u16* Bsl = Bs + sl*(256*64);
        bf16x8 bf_[4][2];
        #pragma unroll
        for(int nt=0;nt<4;++nt)
            #pragma unroll
            for(int ks=0;ks<2;++ks)
                bf_[nt][ks] = *(const bf16x8*)&Bsl[swz(64*wc+16*nt+c, 4*ks+g)];
        if(more){ SB(st2,0,k2); SB(st2,1,k2); SA(st2,0,k2); }
        __builtin_amdgcn_s_setprio(1);
        #pragma unroll
        for(int mt=0;mt<2;++mt){
            bf16x8 a0 = *(const bf16x8*)&Asl[swz(64*wr+16*mt+c, g)];
            bf16x8 a1 = *(const bf16x8*)&Asl[swz(64*wr+16*mt+c, 4+g)];
            #pragma unroll
            for(int nt=0;nt<4;++nt){
                acc[mt][nt] = MFMA(a0, bf_[nt][0], acc[mt][nt]);
                acc[mt][nt] = MFMA(a1, bf_[nt][1], acc[mt][nt]);
            }
        }
        __builtin_amdgcn_s_setprio(0);
        if(more){ SB(st2,2,k2); SB(st2,3,k2); SA(st2,1,k2); }
        __builtin_amdgcn_s_setprio(1);
        #pragma unroll
        for(int mt=2;mt<4;++mt){
            bf16x8 a0 = *(const bf16x8*)&Asl[swz(64*wr+16*mt+c, g)];
            bf16x8 a1 = *(const bf16x8*)&Asl[swz(64*wr+16*mt+c, 4+g)];
            #pragma unroll
            for(int nt=0;nt<4;++nt){
                acc[mt][nt] = MFMA(a0, bf_[nt][0], acc[mt][nt]);
                acc[mt][nt] = MFMA(a1, bf_[nt][1], acc[mt][nt]);
            }
        }
        __builtin_amdgcn_s_setprio(0);
        if(more)           asm volatile("s_waitcnt vmcnt(6)" ::: "memory");
        else if(kt == 14)  asm volatile("s_waitcnt vmcnt(0)" ::: "memory");
        __builtin_amdgcn_s_barrier();
        __builtin_amdgcn_sched_barrier(0);
    }
#undef SA
#undef SB
    const int n0 = by*256 + 64*wc;
    #pragma unroll
    for(int mt=0;mt<4;++mt){
        const int rowb = bx*128 + 64*wr + 16*mt + 4*g;
        #pragma unroll
        for(int nt=0;nt<4;++nt){
            const float bb = bfb[n0+16*nt+c];
            #pragma unroll
            for(int r=0;r<4;++r)
                out[(size_t)(rowb+r)*1024 + n0 + 16*nt + c] = acc[mt][nt][r] + bb;
        }
    }
}

// ============================================================================
extern "C" void kernel_launch(void* const* d_in, const int* in_sizes, int n_in,
                              void* d_out, int out_size, void* d_ws, size_t ws_size,
                              hipStream_t stream){
    (void)in_sizes; (void)n_in; (void)out_size;
    const float* X    = (const float*)d_in[0];
    const float* mask = (const float*)d_in[1];
    const float* Wq   = (const float*)d_in[2];
    const float* bq   = (const float*)d_in[3];
    const float* Wk   = (const float*)d_in[4];
    const float* bk   = (const float*)d_in[5];
    const float* Wv   = (const float*)d_in[6];
    const float* bv   = (const float*)d_in[7];
    const float* Wf   = (const float*)d_in[8];
    const float* bfb  = (const float*)d_in[9];
    const float* proj = (const float*)d_in[10];
    float* out = (float*)d_out;

    char* w = (char*)d_ws;
    size_t off = 0;
    auto alloc = [&](size_t n)->void*{ void* p = w + off; off = (off + n + 255) & ~(size_t)255; return p; };
    u16*   Xb     = (u16*)  alloc((size_t)8192*1024*2);    // X bf16
    u16*   WT     = (u16*)  alloc((size_t)3*1048576*2);    // Wq,Wk,Wv transposed [n][k]
    u16*   Wfh    = (u16*)  alloc((size_t)1048576*2);      // WfT hi
    u16*   pPh    = (u16*)  alloc(16384*2);                // proj packed (bf16)
    u16*   Qb     = (u16*)  alloc((size_t)8192*1024*2);    // normalized Q bf16
    u16*   Kb     = (u16*)  alloc((size_t)8192*1024*2);    // normalized K bf16
    u16*   VT     = (u16*)  alloc((size_t)32*64*4096*2);   // V^T per head bf16
    float* KVpart = (float*)alloc((size_t)32*16*16384*4);  // split-K KV partials
    float* Zpart  = (float*)alloc((size_t)32*16*256*4);
    u16*   KVT    = (u16*)  alloc((size_t)32*64*256*2);    // KV^T [d][m] bf16
    float* Zr     = (float*)alloc((size_t)32*256*4);
    u16*   attnB  = (u16*)  alloc((size_t)8192*1024*2);    // attn bf16
    if (off > ws_size) return;  // ws too small: fail cleanly (output stays zero)

    k_transpose<<<dim3(32,32), 256, 0, stream>>>(Wq, WT,           (u16*)nullptr, 1024, 1024);
    k_transpose<<<dim3(32,32), 256, 0, stream>>>(Wk, WT+1048576,   (u16*)nullptr, 1024, 1024);
    k_transpose<<<dim3(32,32), 256, 0, stream>>>(Wv, WT+2097152,   (u16*)nullptr, 1024, 1024);
    k_transpose<<<dim3(32,32), 256, 0, stream>>>(Wf, Wfh,          (u16*)nullptr, 1024, 1024);
    k_pack_proj<<<dim3(64), 256, 0, stream>>>(proj, pPh);
    k_convertX<<<dim3(8192), 256, 0, stream>>>(X, Xb);
    k_qkv<<<dim3(64,12), 512, 0, stream>>>(Xb, WT, bq, bk, bv, Qb, Kb, VT);
    k_kv<<<dim3(16,32), 256, 0, stream>>>(Kb, pPh, mask, VT, KVpart, Zpart);
    k_kvreduce<<<dim3(512), 256, 0, stream>>>(KVpart, Zpart, KVT, Zr);
    k_attn<<<dim3(64,32), 256, 0, stream>>>(Qb, pPh, KVT, Zr, attnB);
    k_out<<<dim3(64,4), 512, 0, stream>>>(attnB, Wfh, bfb, out);
}

// Round 11
// 223.029 us; speedup vs baseline: 1.1846x; 1.0558x over previous
//
#include <hip/hip_runtime.h>
#include <cmath>

typedef unsigned short u16;
typedef unsigned int   u32;
typedef __attribute__((ext_vector_type(8))) short bf16x8;  // 8 bf16 in 4 VGPRs
typedef __attribute__((ext_vector_type(4))) float f32x4;   // MFMA accumulator

#define DEV __device__ __forceinline__
#define MFMA(a,b,c) __builtin_amdgcn_mfma_f32_16x16x32_bf16((a),(b),(c),0,0,0)

// async global->LDS, 16B per lane: lane l writes dst + l*16 bytes (dst wave-uniform)
#define GLOAD16(dst, src) __builtin_amdgcn_global_load_lds( \
    (const __attribute__((address_space(1))) void*)(src), \
    (__attribute__((address_space(3))) void*)(dst), 16, 0, 0)

// ---- bf16 helpers (RNE) ----
DEV u16 f2bf(float x){ union{float f;u32 u;} v; v.f=x; u32 r=v.u+0x7FFFu+((v.u>>16)&1u); return (u16)(r>>16); }
DEV float bf2f(u16 h){ union{u32 u;float f;} v; v.u=((u32)h)<<16; return v.f; }

// LDS read-side swizzle: within a row (64 elems = 8 col-blocks of 8), XOR the
// col-block with row&7. Same involution on the gload SOURCE col, LDS dest
// linear (rule #21). HW-verified rounds 7-10: conflicts=0, absmax unchanged.
DEV int swz(int row, int cb){ return row*64 + ((cb ^ (row&7))*8); }

// stage one 64x64 unit: 512 threads x 16B; dst linear, src col inverse-swizzled
#define STGU(arr, slotsz, slot, j, P, k0) GLOAD16( \
    &(arr)[(slot)*(slotsz) + ((j)*64 + w*8)*64], \
    (P) + (size_t)((j)*64 + srow_)*1024 + (k0) + scol_)

// ============================================================================
// GEMM core (round-8 proven, ~70.7us in k_qkv): BM=128 x BN=256, BK=64,
// K=1024 (16 tiles), 512 thr = 8 waves (2M x 4N). 3 LDS slots, stage 2 tiles
// ahead (6 gloads/tile), vmcnt(6) once per tile. 2 phases/tile x 16 MFMA.
// ============================================================================
#define GEMM_CORE_128x256(As, Bs, Ap, Bp, acc) do{ \
    const int srow_ = w*8 + (l>>3); \
    const int scol_ = ((l&7) ^ (l>>3))*8; \
    STGU(Bs,256*64,0,0,Bp,0); STGU(Bs,256*64,0,1,Bp,0); STGU(Bs,256*64,0,2,Bp,0); \
    STGU(Bs,256*64,0,3,Bp,0); STGU(As,128*64,0,0,Ap,0); STGU(As,128*64,0,1,Ap,0); \
    STGU(Bs,256*64,1,0,Bp,64); STGU(Bs,256*64,1,1,Bp,64); STGU(Bs,256*64,1,2,Bp,64); \
    STGU(Bs,256*64,1,3,Bp,64); STGU(As,128*64,1,0,Ap,64); STGU(As,128*64,1,1,Ap,64); \
    asm volatile("s_waitcnt vmcnt(6)" ::: "memory"); \
    __builtin_amdgcn_s_barrier(); \
    __builtin_amdgcn_sched_barrier(0); \
    for(int kt=0; kt<16; ++kt){ \
        const int sl = kt % 3; \
        const int st = (kt+2) % 3; \
        const int k2 = (kt+2)*64; \
        const u16* Asl = (As) + sl*(128*64); \
        const u16* Bsl = (Bs) + sl*(256*64); \
        bf16x8 bf_[4][2], af_[2][2]; \
        /* ---- phase 0 ---- */ \
        _Pragma("unroll") \
        for(int nt=0;nt<4;++nt) \
            _Pragma("unroll") \
            for(int ks=0;ks<2;++ks) \
                bf_[nt][ks] = *(const bf16x8*)&Bsl[swz(64*wc+16*nt+c, 4*ks+g)]; \
        _Pragma("unroll") \
        for(int i=0;i<2;++i) \
            _Pragma("unroll") \
            for(int ks=0;ks<2;++ks) \
                af_[i][ks] = *(const bf16x8*)&Asl[swz(64*wr+16*i+c, 4*ks+g)]; \
        if (kt<=13){ STGU(Bs,256*64,st,0,Bp,k2); STGU(Bs,256*64,st,1,Bp,k2); STGU(Bs,256*64,st,2,Bp,k2); } \
        __builtin_amdgcn_s_barrier(); \
        asm volatile("s_waitcnt lgkmcnt(0)" ::: "memory"); \
        __builtin_amdgcn_sched_barrier(0); \
        __builtin_amdgcn_s_setprio(1); \
        _Pragma("unroll") \
        for(int i=0;i<2;++i) \
            _Pragma("unroll") \
            for(int nt=0;nt<4;++nt) \
                _Pragma("unroll") \
                for(int ks=0;ks<2;++ks) \
                    acc[i][nt] = MFMA(af_[i][ks], bf_[nt][ks], acc[i][nt]); \
        __builtin_amdgcn_s_setprio(0); \
        __builtin_amdgcn_s_barrier(); \
        __builtin_amdgcn_sched_barrier(0); \
        /* ---- phase 1 ---- */ \
        _Pragma("unroll") \
        for(int i=0;i<2;++i) \
            _Pragma("unroll") \
            for(int ks=0;ks<2;++ks) \
                af_[i][ks] = *(const bf16x8*)&Asl[swz(64*wr+16*(2+i)+c, 4*ks+g)]; \
        if (kt<=13){ STGU(Bs,256*64,st,3,Bp,k2); STGU(As,128*64,st,0,Ap,k2); STGU(As,128*64,st,1,Ap,k2); } \
        __builtin_amdgcn_s_barrier(); \
        asm volatile("s_waitcnt lgkmcnt(0)" ::: "memory"); \
        __builtin_amdgcn_sched_barrier(0); \
        __builtin_amdgcn_s_setprio(1); \
        _Pragma("unroll") \
        for(int i=0;i<2;++i) \
            _Pragma("unroll") \
            for(int nt=0;nt<4;++nt) \
                _Pragma("unroll") \
                for(int ks=0;ks<2;++ks) \
                    acc[2+i][nt] = MFMA(af_[i][ks], bf_[nt][ks], acc[2+i][nt]); \
        __builtin_amdgcn_s_setprio(0); \
        if (kt<=13)      { asm volatile("s_waitcnt vmcnt(6)" ::: "memory"); } \
        else if (kt==14) { asm volatile("s_waitcnt vmcnt(0)" ::: "memory"); } \
        __builtin_amdgcn_s_barrier(); \
        __builtin_amdgcn_sched_barrier(0); \
    } \
}while(0)

// ============================================================================
// k_prep: ALL prep fused into one dispatch (was 6 dispatches; each dispatch
// costs ~9us of graph-node overhead — rocprof.md launch-overhead trap).
// blocks 0..4095:     transpose Wq/Wk/Wv/Wf fp32[1024][1024] -> bf16 [n][k]
// blocks 4096..12287: convertX  (fp32 -> bf16, 1024 elems/block)
// blocks 12288..12351: pack_proj fragments
// Branch is block-uniform -> __syncthreads inside branch is safe.
// ============================================================================
__global__ __launch_bounds__(256) void k_prep(const float* __restrict__ X,
        const float* __restrict__ Wq, const float* __restrict__ Wk,
        const float* __restrict__ Wv, const float* __restrict__ Wf,
        const float* __restrict__ proj,
        u16* __restrict__ Xb, u16* __restrict__ WT, u16* __restrict__ Wfh,
        u16* __restrict__ pPh){
    const int bid = blockIdx.x, tid = threadIdx.x;
    if (bid < 4096){
        __shared__ float t[32][33];
        const int which = bid >> 10, bb = bid & 1023;
        const float* in = (which==0) ? Wq : (which==1) ? Wk : (which==2) ? Wv : Wf;
        u16* hi = (which==3) ? Wfh : (WT + (size_t)which*1048576);
        const int r0 = (bb>>5)*32, c0 = (bb&31)*32;
        const int lr = tid>>3, lc = (tid&7)*4;
        float4 v = *(const float4*)(in + (size_t)(r0+lr)*1024 + c0 + lc);
        t[lr][lc]=v.x; t[lr][lc+1]=v.y; t[lr][lc+2]=v.z; t[lr][lc+3]=v.w;
        __syncthreads();
        ushort4 o;
        o.x=f2bf(t[lc+0][lr]); o.y=f2bf(t[lc+1][lr]);
        o.z=f2bf(t[lc+2][lr]); o.w=f2bf(t[lc+3][lr]);
        *(ushort4*)(hi + (size_t)(c0+lr)*1024 + r0+lc) = o;
    } else if (bid < 12288){
        size_t i = ((size_t)(bid-4096)*256 + tid)*4;
        float4 v = *(const float4*)(X+i);
        ushort4 o; o.x=f2bf(v.x); o.y=f2bf(v.y); o.z=f2bf(v.z); o.w=f2bf(v.w);
        *(ushort4*)(Xb+i) = o;
    } else {
        int idx = (bid-12288)*256 + tid;          // 0..16383
        int e = idx&7, l = (idx>>3)&63, f = idx>>9;
        int nt = f>>1, ks = f&1;
        int d = 32*ks + 8*(l>>4) + e;
        int m = 16*nt + (l&15);
        pPh[idx] = f2bf(proj[d*256 + m]);
    }
}

// ============================================================================
// k_qkv: C = X @ {Wq,Wk,Wv}; round-8 GEMM core (BM=128/BN=256/BK=64, 3-slot).
// wsel<2: +bias, per-head L2-normalize, store BF16 Qb/Kb [B*S][1024].
// wsel==2: +bias, store bf16 V transposed per head: VT[(b*16+h)*64+d][4096].
// grid (64, 12) = 768 = 3 exact CU rounds: y/4 = wsel, y%4 = 256-col blk.
// ============================================================================
__global__ __launch_bounds__(512,2) void k_qkv(const u16* __restrict__ Xb, const u16* __restrict__ WT,
        const float* __restrict__ bq, const float* __restrict__ bk, const float* __restrict__ bv,
        u16* __restrict__ Qb, u16* __restrict__ Kb, u16* __restrict__ VT){
    __shared__ u16 As[3*128*64];   // 48KB
    __shared__ u16 Bs[3*256*64];   // 96KB
    const int bx = blockIdx.x, y = blockIdx.y;
    const int wsel = y>>2, nb = y&3;
    const int tid = threadIdx.x, w = tid>>6, l = tid&63, g = l>>4, c = l&15;
    const int wr = w>>2, wc = w&3;
    const u16* Ap = Xb + (size_t)bx*128*1024;
    const u16* Bp = WT + (size_t)wsel*1048576 + (size_t)nb*256*1024;
    f32x4 acc[4][4];
    #pragma unroll
    for(int mt=0;mt<4;++mt)
        #pragma unroll
        for(int nt=0;nt<4;++nt) acc[mt][nt] = f32x4{0.f,0.f,0.f,0.f};

    GEMM_CORE_128x256(As, Bs, Ap, Bp, acc);

    const int n0 = nb*256 + 64*wc;    // col within this wsel's 1024
    const int b = bx>>5;
    if (wsel < 2){
        u16* Out = wsel ? Kb : Qb;
        const float* bias = wsel ? bk : bq;
        float bb[4];
        #pragma unroll
        for(int nt=0;nt<4;++nt) bb[nt] = bias[n0+16*nt+c];
        #pragma unroll
        for(int mt=0;mt<4;++mt){
            #pragma unroll
            for(int nt=0;nt<4;++nt)
                #pragma unroll
                for(int r=0;r<4;++r) acc[mt][nt][r] += bb[nt];
            // wave's 64 cols are one head -> norm over nt(4) x shfl16
            #pragma unroll
            for(int r=0;r<4;++r){
                float ss = 0.f;
                #pragma unroll
                for(int nt=0;nt<4;++nt){ float vv = acc[mt][nt][r]; ss += vv*vv; }
                ss += __shfl_xor(ss,1); ss += __shfl_xor(ss,2);
                ss += __shfl_xor(ss,4); ss += __shfl_xor(ss,8);
                float sc = 1.f/(sqrtf(ss)+1e-6f);
                #pragma unroll
                for(int nt=0;nt<4;++nt) acc[mt][nt][r] *= sc;
            }
            const int rowb = bx*128 + 64*wr + 16*mt + 4*g;
            #pragma unroll
            for(int nt=0;nt<4;++nt)
                #pragma unroll
                for(int r=0;r<4;++r)
                    Out[(size_t)(rowb+r)*1024 + n0 + 16*nt + c] = f2bf(acc[mt][nt][r]);
        }
    } else {
        const int h = nb*4 + wc;
        float bb[4];
        #pragma unroll
        for(int nt=0;nt<4;++nt) bb[nt] = bv[n0+16*nt+c];
        #pragma unroll
        for(int mt=0;mt<4;++mt)
            #pragma unroll
            for(int nt=0;nt<4;++nt){
                const int d = 16*nt + c;
                const int s0m = (bx&31)*128 + 64*wr + 16*mt + 4*g;
                ushort4 o;
                o.x = f2bf(acc[mt][nt][0]+bb[nt]); o.y = f2bf(acc[mt][nt][1]+bb[nt]);
                o.z = f2bf(acc[mt][nt][2]+bb[nt]); o.w = f2bf(acc[mt][nt][3]+bb[nt]);
                *(ushort4*)(VT + ((size_t)(b*16+h)*64 + d)*4096 + s0m) = o;
            }
    }
}

// ============================================================================
// k_kv: per (chunk, b*16+h): KV[m,d] = sum_s phiK[s,m] V[s,d]; Z[m] = sum_s phiK
// phiK: single-pass bf16 MFMA (Kb bf16 x pPh bf16). Split-K 16 chunks of 256 s.
// grid (16, 32), 4 waves.
// ============================================================================
__global__ __launch_bounds__(256) void k_kv(const u16* __restrict__ Kb,
        const u16* __restrict__ pPh,
        const float* __restrict__ mask, const u16* __restrict__ VT,
        float* __restrict__ KVpart, float* __restrict__ Zpart){
    __shared__ u16 phiT[256][72];     // [m][s], pad 72
    __shared__ u16 Vs[64][72];        // [d][s]
    __shared__ float zbuf[4][256];
    const int chunk = blockIdx.x, bh = blockIdx.y;
    const int b = bh>>4, h = bh&15;
    const int tid = threadIdx.x, wv = tid>>6, l = tid&63, g = l>>4, c = l&15;
    f32x4 kv[4][4];
    #pragma unroll
    for(int mt=0;mt<4;++mt) for(int dt=0;dt<4;++dt) kv[mt][dt] = f32x4{0.f,0.f,0.f,0.f};
    float zacc[16];
    #pragma unroll
    for(int nt=0;nt<16;++nt) zacc[nt]=0.f;
    const int vd = tid>>2, vs = (tid&3)*16;
    for(int t=0;t<4;++t){
        const int s0 = chunk*256 + t*64;
        __syncthreads();                       // protect prev-iter LDS reads
        { // stage V tile [64 d][64 s]
            const u16* pv = VT + ((size_t)bh*64 + vd)*4096 + s0 + vs;
            uint4 v0 = *(const uint4*)pv, v1 = *(const uint4*)(pv+8);
            *(uint4*)&Vs[vd][vs] = v0; *(uint4*)&Vs[vd][vs+8] = v1;
        }
        // phase A: u = K_head @ proj  (wave w -> s rows 16w..16w+15), single pass
        f32x4 ph[16];
        #pragma unroll
        for(int nt=0;nt<16;++nt) ph[nt] = f32x4{0.f,0.f,0.f,0.f};
        #pragma unroll
        for(int ks=0;ks<2;++ks){
            const int srow = s0 + 16*wv + c;
            bf16x8 ah = *(const bf16x8*)(Kb + (size_t)(b*4096+srow)*1024 + h*64 + 32*ks + 8*g);
            #pragma unroll
            for(int nt=0;nt<16;++nt){
                bf16x8 bh8 = *(const bf16x8*)(pPh + ((size_t)(nt*2+ks)*64 + l)*8);
                ph[nt] = MFMA(ah, bh8, ph[nt]);
            }
        }
        float mk[4];
        #pragma unroll
        for(int r=0;r<4;++r) mk[r] = mask[b*4096 + s0 + 16*wv + 4*g + r];
        #pragma unroll
        for(int nt=0;nt<16;++nt){
            float zs = 0.f;
            #pragma unroll
            for(int r=0;r<4;++r){
                float phv = expf(ph[nt][r]-0.5f)*0.0625f*mk[r];
                phiT[c+16*nt][16*wv+4*g+r] = f2bf(phv);
                zs += phv;
            }
            zacc[nt] += zs;
        }
        __syncthreads();
        // phase B: KV += phiT(A, rows m) x Vs(B, cols d)
        #pragma unroll
        for(int ks=0;ks<2;++ks){
            bf16x8 afr[4], bfr[4];
            #pragma unroll
            for(int mt=0;mt<4;++mt) afr[mt] = *(const bf16x8*)&phiT[64*wv+16*mt+c][32*ks+8*g];
            #pragma unroll
            for(int dt=0;dt<4;++dt) bfr[dt] = *(const bf16x8*)&Vs[16*dt+c][32*ks+8*g];
            #pragma unroll
            for(int mt=0;mt<4;++mt)
                #pragma unroll
                for(int dt=0;dt<4;++dt)
                    kv[mt][dt] = MFMA(afr[mt], bfr[dt], kv[mt][dt]);
        }
    }
    // Z partial
    #pragma unroll
    for(int nt=0;nt<16;++nt){
        float z = zacc[nt];
        z += __shfl_xor(z,16); z += __shfl_xor(z,32);
        if (g==0) zbuf[wv][c+16*nt] = z;
    }
    __syncthreads();
    {
        float z = zbuf[0][tid]+zbuf[1][tid]+zbuf[2][tid]+zbuf[3][tid];
        Zpart[((size_t)bh*16+chunk)*256 + tid] = z;
    }
    float* kout = KVpart + ((size_t)bh*16+chunk)*16384;   // [256 m][64 d]
    #pragma unroll
    for(int mt=0;mt<4;++mt)
        #pragma unroll
        for(int dt=0;dt<4;++dt)
            #pragma unroll
            for(int r=0;r<4;++r)
                kout[(64*wv+16*mt+4*g+r)*64 + 16*dt + c] = kv[mt][dt][r];
}

// ============================================================================
// k_kvreduce (parallel): 512 blocks x 256 threads, one float4 of KV per thread.
// ============================================================================
__global__ __launch_bounds__(256) void k_kvreduce(const float* __restrict__ KVpart,
        const float* __restrict__ Zpart, u16* __restrict__ KVT, float* __restrict__ Z){
    const int gid = blockIdx.x*256 + threadIdx.x;      // 0..131071
    const int bh = gid >> 12;                          // 4096 float4 per bh
    const int i0 = (gid & 4095) * 4;                   // element idx in [256m][64d]
    float4 s = {0.f,0.f,0.f,0.f};
    const float* base = KVpart + (size_t)bh*16*16384 + i0;
    #pragma unroll
    for(int ch=0; ch<16; ++ch){
        float4 v = *(const float4*)(base + (size_t)ch*16384);
        s.x+=v.x; s.y+=v.y; s.z+=v.z; s.w+=v.w;
    }
    const int m = i0 >> 6, d = i0 & 63;                // 4 consecutive d, same m
    u16* dst = KVT + ((size_t)bh*64 + d)*256 + m;
    dst[0]   = f2bf(s.x);
    dst[256] = f2bf(s.y);
    dst[512] = f2bf(s.z);
    dst[768] = f2bf(s.w);
    if (gid < 8192){
        const int zbh = gid >> 8, zm = gid & 255;
        float z = 0.f;
        #pragma unroll
        for(int ch=0; ch<16; ++ch) z += Zpart[((size_t)zbh*16+ch)*256 + zm];
        Z[zbh*256 + zm] = z;
    }
}

// ============================================================================
// k_attn: per (s-tile 64, b*16+h): phiQ single-pass bf16, den via shfl, num
// via MFMA, attn = 8*num/den -> bf16 [B*S][1024]. grid (64, 32), 4 waves.
// ============================================================================
__global__ __launch_bounds__(256) void k_attn(const u16* __restrict__ Qb,
        const u16* __restrict__ pPh,
        const u16* __restrict__ KVT, const float* __restrict__ Z, u16* __restrict__ attn){
    __shared__ u16 phi[64][264];      // [s][m], pad 264
    __shared__ float Zs[256];
    const int st = blockIdx.x, bh = blockIdx.y;
    const int b = bh>>4, h = bh&15;
    const int tid = threadIdx.x, wv = tid>>6, l = tid&63, g = l>>4, c = l&15;
    Zs[tid] = Z[bh*256 + tid];
    const int s0 = st*64;
    f32x4 ph[16];
    #pragma unroll
    for(int nt=0;nt<16;++nt) ph[nt] = f32x4{0.f,0.f,0.f,0.f};
    #pragma unroll
    for(int ks=0;ks<2;++ks){
        const int srow = s0 + 16*wv + c;
        bf16x8 ah = *(const bf16x8*)(Qb + (size_t)(b*4096+srow)*1024 + h*64 + 32*ks + 8*g);
        #pragma unroll
        for(int nt=0;nt<16;++nt){
            bf16x8 bh8 = *(const bf16x8*)(pPh + ((size_t)(nt*2+ks)*64 + l)*8);
            ph[nt] = MFMA(ah, bh8, ph[nt]);
        }
    }
    __syncthreads();                  // Zs visible
    float den[4] = {0.f,0.f,0.f,0.f};
    #pragma unroll
    for(int nt=0;nt<16;++nt){
        float zv = Zs[c+16*nt];
        #pragma unroll
        for(int r=0;r<4;++r){
            float phv = expf(ph[nt][r]-0.5f)*0.0625f;
            den[r] += phv*zv;
            phi[16*wv+4*g+r][c+16*nt] = f2bf(phv);
        }
    }
    #pragma unroll
    for(int r=0;r<4;++r){
        den[r] += __shfl_xor(den[r],1); den[r] += __shfl_xor(den[r],2);
        den[r] += __shfl_xor(den[r],4); den[r] += __shfl_xor(den[r],8);
        den[r] += 1e-6f;
    }
    __syncthreads();                  // phi written
    f32x4 nm[4];
    #pragma unroll
    for(int dt=0;dt<4;++dt) nm[dt] = f32x4{0.f,0.f,0.f,0.f};
    #pragma unroll
    for(int j=0;j<8;++j){
        bf16x8 af = *(const bf16x8*)&phi[16*wv+c][32*j+8*g];
        #pragma unroll
        for(int dt=0;dt<4;++dt){
            bf16x8 bfr = *(const bf16x8*)(KVT + ((size_t)bh*64 + 16*dt + c)*256 + 32*j + 8*g);
            nm[dt] = MFMA(af, bfr, nm[dt]);
        }
    }
    #pragma unroll
    for(int dt=0;dt<4;++dt)
        #pragma unroll
        for(int r=0;r<4;++r){
            const int srow = s0 + 16*wv + 4*g + r;
            attn[(size_t)(b*4096+srow)*1024 + h*64 + 16*dt + c] = f2bf(nm[dt][r]*8.f/den[r]);
        }
}

// ============================================================================
// k_out: out = attn(bf16) @ WfT(bf16) + bf, fp32 out. BM=128 BN=256 BK=64,
// 3 LDS slots, stage 2 tiles ahead, ONE vmcnt(6)+barrier per tile.
// grid (64,4) = 256 = 1 exact CU round.
// ============================================================================
__global__ __launch_bounds__(512,2) void k_out(const u16* __restrict__ attn,
        const u16* __restrict__ Wh, const float* __restrict__ bfb, float* __restrict__ out){
    __shared__ u16 As[3*128*64];   // 48KB
    __shared__ u16 Bs[3*256*64];   // 96KB
    const int bx = blockIdx.x, by = blockIdx.y;
    const int tid = threadIdx.x, w = tid>>6, l = tid&63, g = l>>4, c = l&15;
    const int wr = w>>2, wc = w&3;
    const u16* Ap = attn + (size_t)bx*128*1024;
    const u16* Bp = Wh + (size_t)by*256*1024;
    const int srow_ = w*8 + (l>>3);
    const int scol_ = ((l&7) ^ (l>>3))*8;
#define SA(slot,j,k0) GLOAD16(&As[(slot)*(128*64) + ((j)*64 + w*8)*64], Ap + (size_t)((j)*64 + srow_)*1024 + (k0) + scol_)
#define SB(slot,j,k0) GLOAD16(&Bs[(slot)*(256*64) + ((j)*64 + w*8)*64], Bp + (size_t)((j)*64 + srow_)*1024 + (k0) + scol_)
    f32x4 acc[4][4];
    #pragma unroll
    for(int mt=0;mt<4;++mt)
        #pragma unroll
        for(int nt=0;nt<4;++nt) acc[mt][nt] = f32x4{0.f,0.f,0.f,0.f};
    // prologue: tile0 -> slot0, tile1 -> slot1 (6 units each)
    SB(0,0,0); SB(0,1,0); SB(0,2,0); SB(0,3,0); SA(0,0,0); SA(0,1,0);
    SB(1,0,64); SB(1,1,64); SB(1,2,64); SB(1,3,64); SA(1,0,64); SA(1,1,64);
    asm volatile("s_waitcnt vmcnt(6)" ::: "memory");
    __builtin_amdgcn_s_barrier();
    __builtin_amdgcn_sched_barrier(0);
    for(int kt=0; kt<16; ++kt){
        const int sl = kt%3, st2 = (kt+2)%3, k2 = (kt+2)*64;
        const bool more = kt <= 13;
        const u16* Asl = As + sl*(128*64);
        const u16* Bsl = Bs + sl*(256*64);
        bf16x8 bf_[4][2];
        #pragma unroll
        for(int nt=0;nt<4;++nt)
            #pragma unroll
            for(int ks=0;ks<2;++ks)
                bf_[nt][ks] = *(const bf16x8*)&Bsl[swz(64*wc+16*nt+c, 4*ks+g)];
        if(more){ SB(st2,0,k2); SB(st2,1,k2); SA(st2,0,k2); }
        __builtin_amdgcn_s_setprio(1);
        #pragma unroll
        for(int mt=0;mt<2;++mt){
            bf16x8 a0 = *(const bf16x8*)&Asl[swz(64*wr+16*mt+c, g)];
            bf16x8 a1 = *(const bf16x8*)&Asl[swz(64*wr+16*mt+c, 4+g)];
            #pragma unroll
            for(int nt=0;nt<4;++nt){
                acc[mt][nt] = MFMA(a0, bf_[nt][0], acc[mt][nt]);
                acc[mt][nt] = MFMA(a1, bf_[nt][1], acc[mt][nt]);
            }
        }
        __builtin_amdgcn_s_setprio(0);
        if(more){ SB(st2,2,k2); SB(st2,3,k2); SA(st2,1,k2); }
        __builtin_amdgcn_s_setprio(1);
        #pragma unroll
        for(int mt=2;mt<4;++mt){
            bf16x8 a0 = *(const bf16x8*)&Asl[swz(64*wr+16*mt+c, g)];
            bf16x8 a1 = *(const bf16x8*)&Asl[swz(64*wr+16*mt+c, 4+g)];
            #pragma unroll
            for(int nt=0;nt<4;++nt){
                acc[mt][nt] = MFMA(a0, bf_[nt][0], acc[mt][nt]);
                acc[mt][nt] = MFMA(a1, bf_[nt][1], acc[mt][nt]);
            }
        }
        __builtin_amdgcn_s_setprio(0);
        if(more)           asm volatile("s_waitcnt vmcnt(6)" ::: "memory");
        else if(kt == 14)  asm volatile("s_waitcnt vmcnt(0)" ::: "memory");
        __builtin_amdgcn_s_barrier();
        __builtin_amdgcn_sched_barrier(0);
    }
#undef SA
#undef SB
    const int n0 = by*256 + 64*wc;
    #pragma unroll
    for(int mt=0;mt<4;++mt){
        const int rowb = bx*128 + 64*wr + 16*mt + 4*g;
        #pragma unroll
        for(int nt=0;nt<4;++nt){
            const float bb = bfb[n0+16*nt+c];
            #pragma unroll
            for(int r=0;r<4;++r)
                out[(size_t)(rowb+r)*1024 + n0 + 16*nt + c] = acc[mt][nt][r] + bb;
        }
    }
}

// ============================================================================
extern "C" void kernel_launch(void* const* d_in, const int* in_sizes, int n_in,
                              void* d_out, int out_size, void* d_ws, size_t ws_size,
                              hipStream_t stream){
    (void)in_sizes; (void)n_in; (void)out_size;
    const float* X    = (const float*)d_in[0];
    const float* mask = (const float*)d_in[1];
    const float* Wq   = (const float*)d_in[2];
    const float* bq   = (const float*)d_in[3];
    const float* Wk   = (const float*)d_in[4];
    const float* bk   = (const float*)d_in[5];
    const float* Wv   = (const float*)d_in[6];
    const float* bv   = (const float*)d_in[7];
    const float* Wf   = (const float*)d_in[8];
    const float* bfb  = (const float*)d_in[9];
    const float* proj = (const float*)d_in[10];
    float* out = (float*)d_out;

    char* w = (char*)d_ws;
    size_t off = 0;
    auto alloc = [&](size_t n)->void*{ void* p = w + off; off = (off + n + 255) & ~(size_t)255; return p; };
    u16*   Xb     = (u16*)  alloc((size_t)8192*1024*2);    // X bf16
    u16*   WT     = (u16*)  alloc((size_t)3*1048576*2);    // Wq,Wk,Wv transposed [n][k]
    u16*   Wfh    = (u16*)  alloc((size_t)1048576*2);      // WfT
    u16*   pPh    = (u16*)  alloc(16384*2);                // proj packed (bf16)
    u16*   Qb     = (u16*)  alloc((size_t)8192*1024*2);    // normalized Q bf16
    u16*   Kb     = (u16*)  alloc((size_t)8192*1024*2);    // normalized K bf16
    u16*   VT     = (u16*)  alloc((size_t)32*64*4096*2);   // V^T per head bf16
    float* KVpart = (float*)alloc((size_t)32*16*16384*4);  // split-K KV partials
    float* Zpart  = (float*)alloc((size_t)32*16*256*4);
    u16*   KVT    = (u16*)  alloc((size_t)32*64*256*2);    // KV^T [d][m] bf16
    float* Zr     = (float*)alloc((size_t)32*256*4);
    u16*   attnB  = (u16*)  alloc((size_t)8192*1024*2);    // attn bf16
    if (off > ws_size) return;  // ws too small: fail cleanly (output stays zero)

    k_prep<<<dim3(12352), 256, 0, stream>>>(X, Wq, Wk, Wv, Wf, proj, Xb, WT, Wfh, pPh);
    k_qkv<<<dim3(64,12), 512, 0, stream>>>(Xb, WT, bq, bk, bv, Qb, Kb, VT);
    k_kv<<<dim3(16,32), 256, 0, stream>>>(Kb, pPh, mask, VT, KVpart, Zpart);
    k_kvreduce<<<dim3(512), 256, 0, stream>>>(KVpart, Zpart, KVT, Zr);
    k_attn<<<dim3(64,32), 256, 0, stream>>>(Qb, pPh, KVT, Zr, attnB);
    k_out<<<dim3(64,4), 512, 0, stream>>>(attnB, Wfh, bfb, out);
}

// Round 12
// 220.158 us; speedup vs baseline: 1.2000x; 1.0130x over previous
//
#include <hip/hip_runtime.h>
#include <cmath>

typedef unsigned short u16;
typedef unsigned int   u32;
typedef __attribute__((ext_vector_type(8))) short bf16x8;  // 8 bf16 in 4 VGPRs
typedef __attribute__((ext_vector_type(4))) float f32x4;   // MFMA accumulator

#define DEV __device__ __forceinline__
#define MFMA(a,b,c) __builtin_amdgcn_mfma_f32_16x16x32_bf16((a),(b),(c),0,0,0)

// async global->LDS, 16B per lane: lane l writes dst + l*16 bytes (dst wave-uniform)
#define GLOAD16(dst, src) __builtin_amdgcn_global_load_lds( \
    (const __attribute__((address_space(1))) void*)(src), \
    (__attribute__((address_space(3))) void*)(dst), 16, 0, 0)

// ---- bf16 helpers (RNE) ----
DEV u16 f2bf(float x){ union{float f;u32 u;} v; v.f=x; u32 r=v.u+0x7FFFu+((v.u>>16)&1u); return (u16)(r>>16); }
DEV float bf2f(u16 h){ union{u32 u;float f;} v; v.u=((u32)h)<<16; return v.f; }

// LDS read-side swizzle: within a row (64 elems = 8 col-blocks of 8), XOR the
// col-block with row&7. Same involution on the gload SOURCE col, LDS dest
// linear (rule #21). HW-verified rounds 7-11: conflicts=0, absmax unchanged.
DEV int swz(int row, int cb){ return row*64 + ((cb ^ (row&7))*8); }

// stage one 64x64 unit: 512 threads x 16B; dst linear, src col inverse-swizzled
#define STGU(arr, slotsz, slot, j, P, k0) GLOAD16( \
    &(arr)[(slot)*(slotsz) + ((j)*64 + w*8)*64], \
    (P) + (size_t)((j)*64 + srow_)*1024 + (k0) + scol_)

// ============================================================================
// GEMM core v2 (de-poisoned schedule): BM=128 x BN=256, BK=64, K=1024
// (16 tiles), 512 thr = 8 waves (2M x 4N). 3 LDS slots, stage 2 tiles ahead
// (6 gloads/tile), vmcnt(6) once/tile. ONE barrier/tile; NO forced lgkmcnt(0),
// NO per-phase sched_barrier — the compiler emits fine-grained lgkm waits and
// interleaves ds_read/gload/MFMA itself (m97/m141: forcing order regresses).
// sched_barrier(0) only AFTER the tile barrier: fences next-tile LDS reads
// from hoisting above it (cross-wave staging race).
// ============================================================================
#define GEMM_CORE_128x256(As, Bs, Ap, Bp, acc) do{ \
    const int srow_ = w*8 + (l>>3); \
    const int scol_ = ((l&7) ^ (l>>3))*8; \
    STGU(Bs,256*64,0,0,Bp,0); STGU(Bs,256*64,0,1,Bp,0); STGU(Bs,256*64,0,2,Bp,0); \
    STGU(Bs,256*64,0,3,Bp,0); STGU(As,128*64,0,0,Ap,0); STGU(As,128*64,0,1,Ap,0); \
    STGU(Bs,256*64,1,0,Bp,64); STGU(Bs,256*64,1,1,Bp,64); STGU(Bs,256*64,1,2,Bp,64); \
    STGU(Bs,256*64,1,3,Bp,64); STGU(As,128*64,1,0,Ap,64); STGU(As,128*64,1,1,Ap,64); \
    asm volatile("s_waitcnt vmcnt(6)" ::: "memory"); \
    __builtin_amdgcn_s_barrier(); \
    __builtin_amdgcn_sched_barrier(0); \
    for(int kt=0; kt<16; ++kt){ \
        const int sl = kt % 3; \
        const int st = (kt+2) % 3; \
        const int k2 = (kt+2)*64; \
        const u16* Asl = (As) + sl*(128*64); \
        const u16* Bsl = (Bs) + sl*(256*64); \
        bf16x8 bf_[4][2], af_[4][2]; \
        _Pragma("unroll") \
        for(int nt=0;nt<4;++nt) \
            _Pragma("unroll") \
            for(int ks=0;ks<2;++ks) \
                bf_[nt][ks] = *(const bf16x8*)&Bsl[swz(64*wc+16*nt+c, 4*ks+g)]; \
        _Pragma("unroll") \
        for(int mt=0;mt<4;++mt) \
            _Pragma("unroll") \
            for(int ks=0;ks<2;++ks) \
                af_[mt][ks] = *(const bf16x8*)&Asl[swz(64*wr+16*mt+c, 4*ks+g)]; \
        if (kt<=13){ STGU(Bs,256*64,st,0,Bp,k2); STGU(Bs,256*64,st,1,Bp,k2); STGU(Bs,256*64,st,2,Bp,k2); \
                     STGU(Bs,256*64,st,3,Bp,k2); STGU(As,128*64,st,0,Ap,k2); STGU(As,128*64,st,1,Ap,k2); } \
        _Pragma("unroll") \
        for(int mt=0;mt<4;++mt) \
            _Pragma("unroll") \
            for(int nt=0;nt<4;++nt) \
                _Pragma("unroll") \
                for(int ks=0;ks<2;++ks) \
                    acc[mt][nt] = MFMA(af_[mt][ks], bf_[nt][ks], acc[mt][nt]); \
        if (kt<=13)      { asm volatile("s_waitcnt vmcnt(6)" ::: "memory"); } \
        else if (kt==14) { asm volatile("s_waitcnt vmcnt(0)" ::: "memory"); } \
        __builtin_amdgcn_s_barrier(); \
        __builtin_amdgcn_sched_barrier(0); \
    } \
}while(0)

// ============================================================================
// k_prep: ALL prep fused into one dispatch.
// blocks 0..4095:     transpose Wq/Wk/Wv/Wf fp32[1024][1024] -> bf16 [n][k]
// blocks 4096..12287: convertX  (fp32 -> bf16, 1024 elems/block)
// blocks 12288..12351: pack_proj fragments
// ============================================================================
__global__ __launch_bounds__(256) void k_prep(const float* __restrict__ X,
        const float* __restrict__ Wq, const float* __restrict__ Wk,
        const float* __restrict__ Wv, const float* __restrict__ Wf,
        const float* __restrict__ proj,
        u16* __restrict__ Xb, u16* __restrict__ WT, u16* __restrict__ Wfh,
        u16* __restrict__ pPh){
    const int bid = blockIdx.x, tid = threadIdx.x;
    if (bid < 4096){
        __shared__ float t[32][33];
        const int which = bid >> 10, bb = bid & 1023;
        const float* in = (which==0) ? Wq : (which==1) ? Wk : (which==2) ? Wv : Wf;
        u16* hi = (which==3) ? Wfh : (WT + (size_t)which*1048576);
        const int r0 = (bb>>5)*32, c0 = (bb&31)*32;
        const int lr = tid>>3, lc = (tid&7)*4;
        float4 v = *(const float4*)(in + (size_t)(r0+lr)*1024 + c0 + lc);
        t[lr][lc]=v.x; t[lr][lc+1]=v.y; t[lr][lc+2]=v.z; t[lr][lc+3]=v.w;
        __syncthreads();
        ushort4 o;
        o.x=f2bf(t[lc+0][lr]); o.y=f2bf(t[lc+1][lr]);
        o.z=f2bf(t[lc+2][lr]); o.w=f2bf(t[lc+3][lr]);
        *(ushort4*)(hi + (size_t)(c0+lr)*1024 + r0+lc) = o;
    } else if (bid < 12288){
        size_t i = ((size_t)(bid-4096)*256 + tid)*4;
        float4 v = *(const float4*)(X+i);
        ushort4 o; o.x=f2bf(v.x); o.y=f2bf(v.y); o.z=f2bf(v.z); o.w=f2bf(v.w);
        *(ushort4*)(Xb+i) = o;
    } else {
        int idx = (bid-12288)*256 + tid;          // 0..16383
        int e = idx&7, l = (idx>>3)&63, f = idx>>9;
        int nt = f>>1, ks = f&1;
        int d = 32*ks + 8*(l>>4) + e;
        int m = 16*nt + (l&15);
        pPh[idx] = f2bf(proj[d*256 + m]);
    }
}

// ============================================================================
// k_qkv: C = X @ {Wq,Wk,Wv}; GEMM core v2 (BM=128/BN=256/BK=64, 3-slot).
// wsel<2: +bias, per-head L2-normalize, store BF16 Qb/Kb [B*S][1024].
// wsel==2: +bias, store bf16 V transposed per head: VT[(b*16+h)*64+d][4096].
// grid (64, 12) = 768 = 3 exact CU rounds: y/4 = wsel, y%4 = 256-col blk.
// ============================================================================
__global__ __launch_bounds__(512,2) void k_qkv(const u16* __restrict__ Xb, const u16* __restrict__ WT,
        const float* __restrict__ bq, const float* __restrict__ bk, const float* __restrict__ bv,
        u16* __restrict__ Qb, u16* __restrict__ Kb, u16* __restrict__ VT){
    __shared__ u16 As[3*128*64];   // 48KB
    __shared__ u16 Bs[3*256*64];   // 96KB
    const int bx = blockIdx.x, y = blockIdx.y;
    const int wsel = y>>2, nb = y&3;
    const int tid = threadIdx.x, w = tid>>6, l = tid&63, g = l>>4, c = l&15;
    const int wr = w>>2, wc = w&3;
    const u16* Ap = Xb + (size_t)bx*128*1024;
    const u16* Bp = WT + (size_t)wsel*1048576 + (size_t)nb*256*1024;
    f32x4 acc[4][4];
    #pragma unroll
    for(int mt=0;mt<4;++mt)
        #pragma unroll
        for(int nt=0;nt<4;++nt) acc[mt][nt] = f32x4{0.f,0.f,0.f,0.f};

    GEMM_CORE_128x256(As, Bs, Ap, Bp, acc);

    const int n0 = nb*256 + 64*wc;    // col within this wsel's 1024
    const int b = bx>>5;
    if (wsel < 2){
        u16* Out = wsel ? Kb : Qb;
        const float* bias = wsel ? bk : bq;
        float bb[4];
        #pragma unroll
        for(int nt=0;nt<4;++nt) bb[nt] = bias[n0+16*nt+c];
        #pragma unroll
        for(int mt=0;mt<4;++mt){
            #pragma unroll
            for(int nt=0;nt<4;++nt)
                #pragma unroll
                for(int r=0;r<4;++r) acc[mt][nt][r] += bb[nt];
            // wave's 64 cols are one head -> norm over nt(4) x shfl16
            #pragma unroll
            for(int r=0;r<4;++r){
                float ss = 0.f;
                #pragma unroll
                for(int nt=0;nt<4;++nt){ float vv = acc[mt][nt][r]; ss += vv*vv; }
                ss += __shfl_xor(ss,1); ss += __shfl_xor(ss,2);
                ss += __shfl_xor(ss,4); ss += __shfl_xor(ss,8);
                float sc = 1.f/(sqrtf(ss)+1e-6f);
                #pragma unroll
                for(int nt=0;nt<4;++nt) acc[mt][nt][r] *= sc;
            }
            const int rowb = bx*128 + 64*wr + 16*mt + 4*g;
            #pragma unroll
            for(int nt=0;nt<4;++nt)
                #pragma unroll
                for(int r=0;r<4;++r)
                    Out[(size_t)(rowb+r)*1024 + n0 + 16*nt + c] = f2bf(acc[mt][nt][r]);
        }
    } else {
        const int h = nb*4 + wc;
        float bb[4];
        #pragma unroll
        for(int nt=0;nt<4;++nt) bb[nt] = bv[n0+16*nt+c];
        #pragma unroll
        for(int mt=0;mt<4;++mt)
            #pragma unroll
            for(int nt=0;nt<4;++nt){
                const int d = 16*nt + c;
                const int s0m = (bx&31)*128 + 64*wr + 16*mt + 4*g;
                ushort4 o;
                o.x = f2bf(acc[mt][nt][0]+bb[nt]); o.y = f2bf(acc[mt][nt][1]+bb[nt]);
                o.z = f2bf(acc[mt][nt][2]+bb[nt]); o.w = f2bf(acc[mt][nt][3]+bb[nt]);
                *(ushort4*)(VT + ((size_t)(b*16+h)*64 + d)*4096 + s0m) = o;
            }
    }
}

// ============================================================================
// k_kv: per (chunk, b*16+h): KV[m,d] = sum_s phiK[s,m] V[s,d]; Z[m] = sum_s phiK
// phiK: single-pass bf16 MFMA (Kb bf16 x pPh bf16). Split-K 16 chunks of 256 s.
// grid (16, 32), 4 waves.
// ============================================================================
__global__ __launch_bounds__(256) void k_kv(const u16* __restrict__ Kb,
        const u16* __restrict__ pPh,
        const float* __restrict__ mask, const u16* __restrict__ VT,
        float* __restrict__ KVpart, float* __restrict__ Zpart){
    __shared__ u16 phiT[256][72];     // [m][s], pad 72
    __shared__ u16 Vs[64][72];        // [d][s]
    __shared__ float zbuf[4][256];
    const int chunk = blockIdx.x, bh = blockIdx.y;
    const int b = bh>>4, h = bh&15;
    const int tid = threadIdx.x, wv = tid>>6, l = tid&63, g = l>>4, c = l&15;
    f32x4 kv[4][4];
    #pragma unroll
    for(int mt=0;mt<4;++mt) for(int dt=0;dt<4;++dt) kv[mt][dt] = f32x4{0.f,0.f,0.f,0.f};
    float zacc[16];
    #pragma unroll
    for(int nt=0;nt<16;++nt) zacc[nt]=0.f;
    const int vd = tid>>2, vs = (tid&3)*16;
    for(int t=0;t<4;++t){
        const int s0 = chunk*256 + t*64;
        __syncthreads();                       // protect prev-iter LDS reads
        { // stage V tile [64 d][64 s]
            const u16* pv = VT + ((size_t)bh*64 + vd)*4096 + s0 + vs;
            uint4 v0 = *(const uint4*)pv, v1 = *(const uint4*)(pv+8);
            *(uint4*)&Vs[vd][vs] = v0; *(uint4*)&Vs[vd][vs+8] = v1;
        }
        // phase A: u = K_head @ proj  (wave w -> s rows 16w..16w+15), single pass
        f32x4 ph[16];
        #pragma unroll
        for(int nt=0;nt<16;++nt) ph[nt] = f32x4{0.f,0.f,0.f,0.f};
        #pragma unroll
        for(int ks=0;ks<2;++ks){
            const int srow = s0 + 16*wv + c;
            bf16x8 ah = *(const bf16x8*)(Kb + (size_t)(b*4096+srow)*1024 + h*64 + 32*ks + 8*g);
            #pragma unroll
            for(int nt=0;nt<16;++nt){
                bf16x8 bh8 = *(const bf16x8*)(pPh + ((size_t)(nt*2+ks)*64 + l)*8);
                ph[nt] = MFMA(ah, bh8, ph[nt]);
            }
        }
        float mk[4];
        #pragma unroll
        for(int r=0;r<4;++r) mk[r] = mask[b*4096 + s0 + 16*wv + 4*g + r];
        #pragma unroll
        for(int nt=0;nt<16;++nt){
            float zs = 0.f;
            #pragma unroll
            for(int r=0;r<4;++r){
                float phv = expf(ph[nt][r]-0.5f)*0.0625f*mk[r];
                phiT[c+16*nt][16*wv+4*g+r] = f2bf(phv);
                zs += phv;
            }
            zacc[nt] += zs;
        }
        __syncthreads();
        // phase B: KV += phiT(A, rows m) x Vs(B, cols d)
        #pragma unroll
        for(int ks=0;ks<2;++ks){
            bf16x8 afr[4], bfr[4];
            #pragma unroll
            for(int mt=0;mt<4;++mt) afr[mt] = *(const bf16x8*)&phiT[64*wv+16*mt+c][32*ks+8*g];
            #pragma unroll
            for(int dt=0;dt<4;++dt) bfr[dt] = *(const bf16x8*)&Vs[16*dt+c][32*ks+8*g];
            #pragma unroll
            for(int mt=0;mt<4;++mt)
                #pragma unroll
                for(int dt=0;dt<4;++dt)
                    kv[mt][dt] = MFMA(afr[mt], bfr[dt], kv[mt][dt]);
        }
    }
    // Z partial
    #pragma unroll
    for(int nt=0;nt<16;++nt){
        float z = zacc[nt];
        z += __shfl_xor(z,16); z += __shfl_xor(z,32);
        if (g==0) zbuf[wv][c+16*nt] = z;
    }
    __syncthreads();
    {
        float z = zbuf[0][tid]+zbuf[1][tid]+zbuf[2][tid]+zbuf[3][tid];
        Zpart[((size_t)bh*16+chunk)*256 + tid] = z;
    }
    float* kout = KVpart + ((size_t)bh*16+chunk)*16384;   // [256 m][64 d]
    #pragma unroll
    for(int mt=0;mt<4;++mt)
        #pragma unroll
        for(int dt=0;dt<4;++dt)
            #pragma unroll
            for(int r=0;r<4;++r)
                kout[(64*wv+16*mt+4*g+r)*64 + 16*dt + c] = kv[mt][dt][r];
}

// ============================================================================
// k_kvreduce (parallel): 512 blocks x 256 threads, one float4 of KV per thread.
// ============================================================================
__global__ __launch_bounds__(256) void k_kvreduce(const float* __restrict__ KVpart,
        const float* __restrict__ Zpart, u16* __restrict__ KVT, float* __restrict__ Z){
    const int gid = blockIdx.x*256 + threadIdx.x;      // 0..131071
    const int bh = gid >> 12;                          // 4096 float4 per bh
    const int i0 = (gid & 4095) * 4;                   // element idx in [256m][64d]
    float4 s = {0.f,0.f,0.f,0.f};
    const float* base = KVpart + (size_t)bh*16*16384 + i0;
    #pragma unroll
    for(int ch=0; ch<16; ++ch){
        float4 v = *(const float4*)(base + (size_t)ch*16384);
        s.x+=v.x; s.y+=v.y; s.z+=v.z; s.w+=v.w;
    }
    const int m = i0 >> 6, d = i0 & 63;                // 4 consecutive d, same m
    u16* dst = KVT + ((size_t)bh*64 + d)*256 + m;
    dst[0]   = f2bf(s.x);
    dst[256] = f2bf(s.y);
    dst[512] = f2bf(s.z);
    dst[768] = f2bf(s.w);
    if (gid < 8192){
        const int zbh = gid >> 8, zm = gid & 255;
        float z = 0.f;
        #pragma unroll
        for(int ch=0; ch<16; ++ch) z += Zpart[((size_t)zbh*16+ch)*256 + zm];
        Z[zbh*256 + zm] = z;
    }
}

// ============================================================================
// k_attn: per (s-tile 64, b*16+h): phiQ single-pass bf16, den via shfl, num
// via MFMA, attn = 8*num/den -> bf16 [B*S][1024]. grid (64, 32), 4 waves.
// ============================================================================
__global__ __launch_bounds__(256) void k_attn(const u16* __restrict__ Qb,
        const u16* __restrict__ pPh,
        const u16* __restrict__ KVT, const float* __restrict__ Z, u16* __restrict__ attn){
    __shared__ u16 phi[64][264];      // [s][m], pad 264
    __shared__ float Zs[256];
    const int st = blockIdx.x, bh = blockIdx.y;
    const int b = bh>>4, h = bh&15;
    const int tid = threadIdx.x, wv = tid>>6, l = tid&63, g = l>>4, c = l&15;
    Zs[tid] = Z[bh*256 + tid];
    const int s0 = st*64;
    f32x4 ph[16];
    #pragma unroll
    for(int nt=0;nt<16;++nt) ph[nt] = f32x4{0.f,0.f,0.f,0.f};
    #pragma unroll
    for(int ks=0;ks<2;++ks){
        const int srow = s0 + 16*wv + c;
        bf16x8 ah = *(const bf16x8*)(Qb + (size_t)(b*4096+srow)*1024 + h*64 + 32*ks + 8*g);
        #pragma unroll
        for(int nt=0;nt<16;++nt){
            bf16x8 bh8 = *(const bf16x8*)(pPh + ((size_t)(nt*2+ks)*64 + l)*8);
            ph[nt] = MFMA(ah, bh8, ph[nt]);
        }
    }
    __syncthreads();                  // Zs visible
    float den[4] = {0.f,0.f,0.f,0.f};
    #pragma unroll
    for(int nt=0;nt<16;++nt){
        float zv = Zs[c+16*nt];
        #pragma unroll
        for(int r=0;r<4;++r){
            float phv = expf(ph[nt][r]-0.5f)*0.0625f;
            den[r] += phv*zv;
            phi[16*wv+4*g+r][c+16*nt] = f2bf(phv);
        }
    }
    #pragma unroll
    for(int r=0;r<4;++r){
        den[r] += __shfl_xor(den[r],1); den[r] += __shfl_xor(den[r],2);
        den[r] += __shfl_xor(den[r],4); den[r] += __shfl_xor(den[r],8);
        den[r] += 1e-6f;
    }
    __syncthreads();                  // phi written
    f32x4 nm[4];
    #pragma unroll
    for(int dt=0;dt<4;++dt) nm[dt] = f32x4{0.f,0.f,0.f,0.f};
    #pragma unroll
    for(int j=0;j<8;++j){
        bf16x8 af = *(const bf16x8*)&phi[16*wv+c][32*j+8*g];
        #pragma unroll
        for(int dt=0;dt<4;++dt){
            bf16x8 bfr = *(const bf16x8*)(KVT + ((size_t)bh*64 + 16*dt + c)*256 + 32*j + 8*g);
            nm[dt] = MFMA(af, bfr, nm[dt]);
        }
    }
    #pragma unroll
    for(int dt=0;dt<4;++dt)
        #pragma unroll
        for(int r=0;r<4;++r){
            const int srow = s0 + 16*wv + 4*g + r;
            attn[(size_t)(b*4096+srow)*1024 + h*64 + 16*dt + c] = f2bf(nm[dt][r]*8.f/den[r]);
        }
}

// ============================================================================
// k_out: out = attn(bf16) @ WfT(bf16) + bf, fp32 out. GEMM core v2.
// grid (64,4) = 256 = 1 exact CU round.
// ============================================================================
__global__ __launch_bounds__(512,2) void k_out(const u16* __restrict__ attn,
        const u16* __restrict__ Wh, const float* __restrict__ bfb, float* __restrict__ out){
    __shared__ u16 As[3*128*64];   // 48KB
    __shared__ u16 Bs[3*256*64];   // 96KB
    const int bx = blockIdx.x, by = blockIdx.y;
    const int tid = threadIdx.x, w = tid>>6, l = tid&63, g = l>>4, c = l&15;
    const int wr = w>>2, wc = w&3;
    const u16* Ap = attn + (size_t)bx*128*1024;
    const u16* Bp = Wh + (size_t)by*256*1024;
    f32x4 acc[4][4];
    #pragma unroll
    for(int mt=0;mt<4;++mt)
        #pragma unroll
        for(int nt=0;nt<4;++nt) acc[mt][nt] = f32x4{0.f,0.f,0.f,0.f};

    GEMM_CORE_128x256(As, Bs, Ap, Bp, acc);

    const int n0 = by*256 + 64*wc;
    #pragma unroll
    for(int mt=0;mt<4;++mt){
        const int rowb = bx*128 + 64*wr + 16*mt + 4*g;
        #pragma unroll
        for(int nt=0;nt<4;++nt){
            const float bb = bfb[n0+16*nt+c];
            #pragma unroll
            for(int r=0;r<4;++r)
                out[(size_t)(rowb+r)*1024 + n0 + 16*nt + c] = acc[mt][nt][r] + bb;
        }
    }
}

// ============================================================================
extern "C" void kernel_launch(void* const* d_in, const int* in_sizes, int n_in,
                              void* d_out, int out_size, void* d_ws, size_t ws_size,
                              hipStream_t stream){
    (void)in_sizes; (void)n_in; (void)out_size;
    const float* X    = (const float*)d_in[0];
    const float* mask = (const float*)d_in[1];
    const float* Wq   = (const float*)d_in[2];
    const float* bq   = (const float*)d_in[3];
    const float* Wk   = (const float*)d_in[4];
    const float* bk   = (const float*)d_in[5];
    const float* Wv   = (const float*)d_in[6];
    const float* bv   = (const float*)d_in[7];
    const float* Wf   = (const float*)d_in[8];
    const float* bfb  = (const float*)d_in[9];
    const float* proj = (const float*)d_in[10];
    float* out = (float*)d_out;

    char* w = (char*)d_ws;
    size_t off = 0;
    auto alloc = [&](size_t n)->void*{ void* p = w + off; off = (off + n + 255) & ~(size_t)255; return p; };
    u16*   Xb     = (u16*)  alloc((size_t)8192*1024*2);    // X bf16
    u16*   WT     = (u16*)  alloc((size_t)3*1048576*2);    // Wq,Wk,Wv transposed [n][k]
    u16*   Wfh    = (u16*)  alloc((size_t)1048576*2);      // WfT
    u16*   pPh    = (u16*)  alloc(16384*2);                // proj packed (bf16)
    u16*   Qb     = (u16*)  alloc((size_t)8192*1024*2);    // normalized Q bf16
    u16*   Kb     = (u16*)  alloc((size_t)8192*1024*2);    // normalized K bf16
    u16*   VT     = (u16*)  alloc((size_t)32*64*4096*2);   // V^T per head bf16
    float* KVpart = (float*)alloc((size_t)32*16*16384*4);  // split-K KV partials
    float* Zpart  = (float*)alloc((size_t)32*16*256*4);
    u16*   KVT    = (u16*)  alloc((size_t)32*64*256*2);    // KV^T [d][m] bf16
    float* Zr     = (float*)alloc((size_t)32*256*4);
    u16*   attnB  = (u16*)  alloc((size_t)8192*1024*2);    // attn bf16
    if (off > ws_size) return;  // ws too small: fail cleanly (output stays zero)

    k_prep<<<dim3(12352), 256, 0, stream>>>(X, Wq, Wk, Wv, Wf, proj, Xb, WT, Wfh, pPh);
    k_qkv<<<dim3(64,12), 512, 0, stream>>>(Xb, WT, bq, bk, bv, Qb, Kb, VT);
    k_kv<<<dim3(16,32), 256, 0, stream>>>(Kb, pPh, mask, VT, KVpart, Zpart);
    k_kvreduce<<<dim3(512), 256, 0, stream>>>(KVpart, Zpart, KVT, Zr);
    k_attn<<<dim3(64,32), 256, 0, stream>>>(Qb, pPh, KVT, Zr, attnB);
    k_out<<<dim3(64,4), 512, 0, stream>>>(attnB, Wfh, bfb, out);
}

// Round 14
// 171.312 us; speedup vs baseline: 1.5422x; 1.2851x over previous
//
#include <hip/hip_runtime.h>
#include <cmath>

typedef unsigned short u16;
typedef unsigned int   u32;
typedef __attribute__((ext_vector_type(8))) short bf16x8;  // 8 bf16 in 4 VGPRs
typedef __attribute__((ext_vector_type(4))) float f32x4;   // MFMA accumulator

#define DEV __device__ __forceinline__
#define MFMA(a,b,c) __builtin_amdgcn_mfma_f32_16x16x32_bf16((a),(b),(c),0,0,0)

// async global->LDS, 16B per lane: lane l writes dst + l*16 bytes (dst wave-uniform;
// global source address is PER-LANE)
#define GLOAD16(dst, src) __builtin_amdgcn_global_load_lds( \
    (const __attribute__((address_space(1))) void*)(src), \
    (__attribute__((address_space(3))) void*)(dst), 16, 0, 0)

// ---- bf16 helpers (RNE) ----
DEV u16 f2bf(float x){ union{float f;u32 u;} v; v.f=x; u32 r=v.u+0x7FFFu+((v.u>>16)&1u); return (u16)(r>>16); }
DEV float bf2f(u16 h){ union{u32 u;float f;} v; v.u=((u32)h)<<16; return v.f; }

// LDS read-side swizzle: within a row (64 elems = 8 col-blocks of 8), XOR the
// col-block with row&7. Same involution on the gload SOURCE col, LDS dest
// linear (rule #21). HW-verified rounds 7-12: conflicts=0, absmax unchanged.
DEV int swz(int row, int cb){ return row*64 + ((cb ^ (row&7))*8); }

// stage one 64x64 unit: 512 threads x 16B; dst linear, src col inverse-swizzled
#define STGU(arr, slotsz, slot, j, P, k0) GLOAD16( \
    &(arr)[(slot)*(slotsz) + ((j)*64 + w*8)*64], \
    (P) + (size_t)((j)*64 + srow_)*1024 + (k0) + scol_)

// ============================================================================
// GEMM core v2 (de-poisoned schedule, round-12): BM=128 x BN=256, BK=64,
// K=1024 (16 tiles), 512 thr = 8 waves (2M x 4N). 3 LDS slots, stage 2 tiles
// ahead (6 gloads/tile), vmcnt(6) once/tile, ONE barrier/tile.
// ============================================================================
#define GEMM_CORE_128x256(As, Bs, Ap, Bp, acc) do{ \
    const int srow_ = w*8 + (l>>3); \
    const int scol_ = ((l&7) ^ (l>>3))*8; \
    STGU(Bs,256*64,0,0,Bp,0); STGU(Bs,256*64,0,1,Bp,0); STGU(Bs,256*64,0,2,Bp,0); \
    STGU(Bs,256*64,0,3,Bp,0); STGU(As,128*64,0,0,Ap,0); STGU(As,128*64,0,1,Ap,0); \
    STGU(Bs,256*64,1,0,Bp,64); STGU(Bs,256*64,1,1,Bp,64); STGU(Bs,256*64,1,2,Bp,64); \
    STGU(Bs,256*64,1,3,Bp,64); STGU(As,128*64,1,0,Ap,64); STGU(As,128*64,1,1,Ap,64); \
    asm volatile("s_waitcnt vmcnt(6)" ::: "memory"); \
    __builtin_amdgcn_s_barrier(); \
    __builtin_amdgcn_sched_barrier(0); \
    for(int kt=0; kt<16; ++kt){ \
        const int sl = kt % 3; \
        const int st = (kt+2) % 3; \
        const int k2 = (kt+2)*64; \
        const u16* Asl = (As) + sl*(128*64); \
        const u16* Bsl = (Bs) + sl*(256*64); \
        bf16x8 bf_[4][2], af_[4][2]; \
        _Pragma("unroll") \
        for(int nt=0;nt<4;++nt) \
            _Pragma("unroll") \
            for(int ks=0;ks<2;++ks) \
                bf_[nt][ks] = *(const bf16x8*)&Bsl[swz(64*wc+16*nt+c, 4*ks+g)]; \
        _Pragma("unroll") \
        for(int mt=0;mt<4;++mt) \
            _Pragma("unroll") \
            for(int ks=0;ks<2;++ks) \
                af_[mt][ks] = *(const bf16x8*)&Asl[swz(64*wr+16*mt+c, 4*ks+g)]; \
        if (kt<=13){ STGU(Bs,256*64,st,0,Bp,k2); STGU(Bs,256*64,st,1,Bp,k2); STGU(Bs,256*64,st,2,Bp,k2); \
                     STGU(Bs,256*64,st,3,Bp,k2); STGU(As,128*64,st,0,Ap,k2); STGU(As,128*64,st,1,Ap,k2); } \
        _Pragma("unroll") \
        for(int mt=0;mt<4;++mt) \
            _Pragma("unroll") \
            for(int nt=0;nt<4;++nt) \
                _Pragma("unroll") \
                for(int ks=0;ks<2;++ks) \
                    acc[mt][nt] = MFMA(af_[mt][ks], bf_[nt][ks], acc[mt][nt]); \
        if (kt<=13)      { asm volatile("s_waitcnt vmcnt(6)" ::: "memory"); } \
        else if (kt==14) { asm volatile("s_waitcnt vmcnt(0)" ::: "memory"); } \
        __builtin_amdgcn_s_barrier(); \
        __builtin_amdgcn_sched_barrier(0); \
    } \
}while(0)

// ============================================================================
// k_prep: ALL prep fused into one dispatch.
// ============================================================================
__global__ __launch_bounds__(256) void k_prep(const float* __restrict__ X,
        const float* __restrict__ Wq, const float* __restrict__ Wk,
        const float* __restrict__ Wv, const float* __restrict__ Wf,
        const float* __restrict__ proj,
        u16* __restrict__ Xb, u16* __restrict__ WT, u16* __restrict__ Wfh,
        u16* __restrict__ pPh){
    const int bid = blockIdx.x, tid = threadIdx.x;
    if (bid < 4096){
        __shared__ float t[32][33];
        const int which = bid >> 10, bb = bid & 1023;
        const float* in = (which==0) ? Wq : (which==1) ? Wk : (which==2) ? Wv : Wf;
        u16* hi = (which==3) ? Wfh : (WT + (size_t)which*1048576);
        const int r0 = (bb>>5)*32, c0 = (bb&31)*32;
        const int lr = tid>>3, lc = (tid&7)*4;
        float4 v = *(const float4*)(in + (size_t)(r0+lr)*1024 + c0 + lc);
        t[lr][lc]=v.x; t[lr][lc+1]=v.y; t[lr][lc+2]=v.z; t[lr][lc+3]=v.w;
        __syncthreads();
        ushort4 o;
        o.x=f2bf(t[lc+0][lr]); o.y=f2bf(t[lc+1][lr]);
        o.z=f2bf(t[lc+2][lr]); o.w=f2bf(t[lc+3][lr]);
        *(ushort4*)(hi + (size_t)(c0+lr)*1024 + r0+lc) = o;
    } else if (bid < 12288){
        size_t i = ((size_t)(bid-4096)*256 + tid)*4;
        float4 v = *(const float4*)(X+i);
        ushort4 o; o.x=f2bf(v.x); o.y=f2bf(v.y); o.z=f2bf(v.z); o.w=f2bf(v.w);
        *(ushort4*)(Xb+i) = o;
    } else {
        int idx = (bid-12288)*256 + tid;          // 0..16383
        int e = idx&7, l = (idx>>3)&63, f = idx>>9;
        int nt = f>>1, ks = f&1;
        int d = 32*ks + 8*(l>>4) + e;
        int m = 16*nt + (l&15);
        pPh[idx] = f2bf(proj[d*256 + m]);
    }
}

// ============================================================================
// k_qkv: C = X @ {Wq,Wk,Wv}; GEMM core v2. grid (64,12) = 768 = 3 CU rounds.
// ============================================================================
__global__ __launch_bounds__(512,2) void k_qkv(const u16* __restrict__ Xb, const u16* __restrict__ WT,
        const float* __restrict__ bq, const float* __restrict__ bk, const float* __restrict__ bv,
        u16* __restrict__ Qb, u16* __restrict__ Kb, u16* __restrict__ VT){
    __shared__ u16 As[3*128*64];   // 48KB
    __shared__ u16 Bs[3*256*64];   // 96KB
    const int bx = blockIdx.x, y = blockIdx.y;
    const int wsel = y>>2, nb = y&3;
    const int tid = threadIdx.x, w = tid>>6, l = tid&63, g = l>>4, c = l&15;
    const int wr = w>>2, wc = w&3;
    const u16* Ap = Xb + (size_t)bx*128*1024;
    const u16* Bp = WT + (size_t)wsel*1048576 + (size_t)nb*256*1024;
    f32x4 acc[4][4];
    #pragma unroll
    for(int mt=0;mt<4;++mt)
        #pragma unroll
        for(int nt=0;nt<4;++nt) acc[mt][nt] = f32x4{0.f,0.f,0.f,0.f};

    GEMM_CORE_128x256(As, Bs, Ap, Bp, acc);

    const int n0 = nb*256 + 64*wc;    // col within this wsel's 1024
    const int b = bx>>5;
    if (wsel < 2){
        u16* Out = wsel ? Kb : Qb;
        const float* bias = wsel ? bk : bq;
        float bb[4];
        #pragma unroll
        for(int nt=0;nt<4;++nt) bb[nt] = bias[n0+16*nt+c];
        #pragma unroll
        for(int mt=0;mt<4;++mt){
            #pragma unroll
            for(int nt=0;nt<4;++nt)
                #pragma unroll
                for(int r=0;r<4;++r) acc[mt][nt][r] += bb[nt];
            // wave's 64 cols are one head -> norm over nt(4) x shfl16
            #pragma unroll
            for(int r=0;r<4;++r){
                float ss = 0.f;
                #pragma unroll
                for(int nt=0;nt<4;++nt){ float vv = acc[mt][nt][r]; ss += vv*vv; }
                ss += __shfl_xor(ss,1); ss += __shfl_xor(ss,2);
                ss += __shfl_xor(ss,4); ss += __shfl_xor(ss,8);
                float sc = 1.f/(sqrtf(ss)+1e-6f);
                #pragma unroll
                for(int nt=0;nt<4;++nt) acc[mt][nt][r] *= sc;
            }
            const int rowb = bx*128 + 64*wr + 16*mt + 4*g;
            #pragma unroll
            for(int nt=0;nt<4;++nt)
                #pragma unroll
                for(int r=0;r<4;++r)
                    Out[(size_t)(rowb+r)*1024 + n0 + 16*nt + c] = f2bf(acc[mt][nt][r]);
        }
    } else {
        const int h = nb*4 + wc;
        float bb[4];
        #pragma unroll
        for(int nt=0;nt<4;++nt) bb[nt] = bv[n0+16*nt+c];
        #pragma unroll
        for(int mt=0;mt<4;++mt)
            #pragma unroll
            for(int nt=0;nt<4;++nt){
                const int d = 16*nt + c;
                const int s0m = (bx&31)*128 + 64*wr + 16*mt + 4*g;
                ushort4 o;
                o.x = f2bf(acc[mt][nt][0]+bb[nt]); o.y = f2bf(acc[mt][nt][1]+bb[nt]);
                o.z = f2bf(acc[mt][nt][2]+bb[nt]); o.w = f2bf(acc[mt][nt][3]+bb[nt]);
                *(ushort4*)(VT + ((size_t)(b*16+h)*64 + d)*4096 + s0m) = o;
            }
    }
}

// ============================================================================
// k_kv: per (chunk, b*16+h): KV[m,d] = sum_s phiK[s,m] V[s,d]; Z[m] = sum_s phiK
// phiK single-pass bf16; exp via __expf (v_exp_f32, rel-err ~1e-7 << budget).
// Split-K 16 chunks of 256 s. grid (16, 32), 4 waves.
// ============================================================================
__global__ __launch_bounds__(256) void k_kv(const u16* __restrict__ Kb,
        const u16* __restrict__ pPh,
        const float* __restrict__ mask, const u16* __restrict__ VT,
        float* __restrict__ KVpart, float* __restrict__ Zpart){
    __shared__ u16 phiT[256][72];     // [m][s], pad 72
    __shared__ u16 Vs[64][72];        // [d][s]
    __shared__ float zbuf[4][256];
    const int chunk = blockIdx.x, bh = blockIdx.y;
    const int b = bh>>4, h = bh&15;
    const int tid = threadIdx.x, wv = tid>>6, l = tid&63, g = l>>4, c = l&15;
    f32x4 kv[4][4];
    #pragma unroll
    for(int mt=0;mt<4;++mt) for(int dt=0;dt<4;++dt) kv[mt][dt] = f32x4{0.f,0.f,0.f,0.f};
    float zacc[16];
    #pragma unroll
    for(int nt=0;nt<16;++nt) zacc[nt]=0.f;
    const int vd = tid>>2, vs = (tid&3)*16;
    for(int t=0;t<4;++t){
        const int s0 = chunk*256 + t*64;
        __syncthreads();                       // protect prev-iter LDS reads
        { // stage V tile [64 d][64 s]
            const u16* pv = VT + ((size_t)bh*64 + vd)*4096 + s0 + vs;
            uint4 v0 = *(const uint4*)pv, v1 = *(const uint4*)(pv+8);
            *(uint4*)&Vs[vd][vs] = v0; *(uint4*)&Vs[vd][vs+8] = v1;
        }
        // phase A: u = K_head @ proj  (wave w -> s rows 16w..16w+15), single pass
        f32x4 ph[16];
        #pragma unroll
        for(int nt=0;nt<16;++nt) ph[nt] = f32x4{0.f,0.f,0.f,0.f};
        #pragma unroll
        for(int ks=0;ks<2;++ks){
            const int srow = s0 + 16*wv + c;
            bf16x8 ah = *(const bf16x8*)(Kb + (size_t)(b*4096+srow)*1024 + h*64 + 32*ks + 8*g);
            #pragma unroll
            for(int nt=0;nt<16;++nt){
                bf16x8 bh8 = *(const bf16x8*)(pPh + ((size_t)(nt*2+ks)*64 + l)*8);
                ph[nt] = MFMA(ah, bh8, ph[nt]);
            }
        }
        float mk[4];
        #pragma unroll
        for(int r=0;r<4;++r) mk[r] = mask[b*4096 + s0 + 16*wv + 4*g + r];
        #pragma unroll
        for(int nt=0;nt<16;++nt){
            float zs = 0.f;
            #pragma unroll
            for(int r=0;r<4;++r){
                float phv = __expf(ph[nt][r]-0.5f)*0.0625f*mk[r];
                phiT[c+16*nt][16*wv+4*g+r] = f2bf(phv);
                zs += phv;
            }
            zacc[nt] += zs;
        }
        __syncthreads();
        // phase B: KV += phiT(A, rows m) x Vs(B, cols d)
        #pragma unroll
        for(int ks=0;ks<2;++ks){
            bf16x8 afr[4], bfr[4];
            #pragma unroll
            for(int mt=0;mt<4;++mt) afr[mt] = *(const bf16x8*)&phiT[64*wv+16*mt+c][32*ks+8*g];
            #pragma unroll
            for(int dt=0;dt<4;++dt) bfr[dt] = *(const bf16x8*)&Vs[16*dt+c][32*ks+8*g];
            #pragma unroll
            for(int mt=0;mt<4;++mt)
                #pragma unroll
                for(int dt=0;dt<4;++dt)
                    kv[mt][dt] = MFMA(afr[mt], bfr[dt], kv[mt][dt]);
        }
    }
    // Z partial
    #pragma unroll
    for(int nt=0;nt<16;++nt){
        float z = zacc[nt];
        z += __shfl_xor(z,16); z += __shfl_xor(z,32);
        if (g==0) zbuf[wv][c+16*nt] = z;
    }
    __syncthreads();
    {
        float z = zbuf[0][tid]+zbuf[1][tid]+zbuf[2][tid]+zbuf[3][tid];
        Zpart[((size_t)bh*16+chunk)*256 + tid] = z;
    }
    float* kout = KVpart + ((size_t)bh*16+chunk)*16384;   // [256 m][64 d]
    #pragma unroll
    for(int mt=0;mt<4;++mt)
        #pragma unroll
        for(int dt=0;dt<4;++dt)
            #pragma unroll
            for(int r=0;r<4;++r)
                kout[(64*wv+16*mt+4*g+r)*64 + 16*dt + c] = kv[mt][dt][r];
}

// ============================================================================
// k_kvreduce (parallel): 512 blocks x 256 threads, one float4 of KV per thread.
// ============================================================================
__global__ __launch_bounds__(256) void k_kvreduce(const float* __restrict__ KVpart,
        const float* __restrict__ Zpart, u16* __restrict__ KVT, float* __restrict__ Z){
    const int gid = blockIdx.x*256 + threadIdx.x;      // 0..131071
    const int bh = gid >> 12;                          // 4096 float4 per bh
    const int i0 = (gid & 4095) * 4;                   // element idx in [256m][64d]
    float4 s = {0.f,0.f,0.f,0.f};
    const float* base = KVpart + (size_t)bh*16*16384 + i0;
    #pragma unroll
    for(int ch=0; ch<16; ++ch){
        float4 v = *(const float4*)(base + (size_t)ch*16384);
        s.x+=v.x; s.y+=v.y; s.z+=v.z; s.w+=v.w;
    }
    const int m = i0 >> 6, d = i0 & 63;                // 4 consecutive d, same m
    u16* dst = KVT + ((size_t)bh*64 + d)*256 + m;
    dst[0]   = f2bf(s.x);
    dst[256] = f2bf(s.y);
    dst[512] = f2bf(s.z);
    dst[768] = f2bf(s.w);
    if (gid < 8192){
        const int zbh = gid >> 8, zm = gid & 255;
        float z = 0.f;
        #pragma unroll
        for(int ch=0; ch<16; ++ch) z += Zpart[((size_t)zbh*16+ch)*256 + zm];
        Z[zbh*256 + zm] = z;
    }
}

// ============================================================================
// k_attn v2: grid (8, 32) = 256 blocks = 1 CU round, 512 thr = 8 waves.
// Stage KVT (32KB, XOR-swizzled via pre-swizzled gload source) + pPh (32KB,
// linear) + Z in LDS ONCE; then 4 tiles x 128 s-rows with ALL MFMA operands
// LDS-resident. phi[128][264] scratch for the C-layout -> A-layout shuffle.
// exp via __expf.
// ============================================================================
__global__ __launch_bounds__(512) void k_attn(const u16* __restrict__ Qb,
        const u16* __restrict__ pPh,
        const u16* __restrict__ KVT, const float* __restrict__ Z, u16* __restrict__ attn){
    __shared__ u16 kvs[64*256];       // 32KB, row d, swizzled col-blocks
    __shared__ u16 pps[16384];        // 32KB, linear copy of pPh
    __shared__ u16 phi[128][264];     // 67.5KB
    __shared__ float Zs[256];
    const int bx = blockIdx.x, bh = blockIdx.y;
    const int b = bh>>4, h = bh&15;
    const int tid = threadIdx.x, w = tid>>6, l = tid&63, g = l>>4, c = l&15;
    if (tid < 256) Zs[tid] = Z[bh*256 + tid];
    // stage kvs: 32 gload units of 2 rows; dst linear, src col-block pre-swizzled
    #pragma unroll
    for(int j2=0;j2<4;++j2){
        const int base_row = (j2*8 + w)*2;
        const int row = base_row + (l>>5), cb = l&31;
        GLOAD16(kvs + base_row*256,
                KVT + (size_t)bh*16384 + row*256 + ((cb ^ (row&7))*8));
    }
    // stage pps: straight linear copy
    #pragma unroll
    for(int j2=0;j2<4;++j2){
        const int base = (j2*8 + w)*512;
        GLOAD16(pps + base, pPh + base + l*8);
    }
    asm volatile("s_waitcnt vmcnt(0)" ::: "memory");
    __syncthreads();

    for(int t=0;t<4;++t){
        const int s0 = bx*512 + t*128;
        // phiQ: u = Q_head @ proj (wave w -> s rows s0+16w .. +15)
        f32x4 ph[16];
        #pragma unroll
        for(int nt=0;nt<16;++nt) ph[nt] = f32x4{0.f,0.f,0.f,0.f};
        #pragma unroll
        for(int ks=0;ks<2;++ks){
            const int srow = s0 + 16*w + c;
            bf16x8 ah = *(const bf16x8*)(Qb + (size_t)(b*4096+srow)*1024 + h*64 + 32*ks + 8*g);
            #pragma unroll
            for(int nt=0;nt<16;++nt){
                bf16x8 bh8 = *(const bf16x8*)(pps + ((nt*2+ks)*64 + l)*8);
                ph[nt] = MFMA(ah, bh8, ph[nt]);
            }
        }
        float den[4] = {0.f,0.f,0.f,0.f};
        #pragma unroll
        for(int nt=0;nt<16;++nt){
            float zv = Zs[c+16*nt];
            #pragma unroll
            for(int r=0;r<4;++r){
                float phv = __expf(ph[nt][r]-0.5f)*0.0625f;
                den[r] += phv*zv;
                phi[16*w+4*g+r][c+16*nt] = f2bf(phv);
            }
        }
        #pragma unroll
        for(int r=0;r<4;++r){
            den[r] += __shfl_xor(den[r],1); den[r] += __shfl_xor(den[r],2);
            den[r] += __shfl_xor(den[r],4); den[r] += __shfl_xor(den[r],8);
            den[r] += 1e-6f;
        }
        __syncthreads();              // phi written
        f32x4 nm[4];
        #pragma unroll
        for(int dt=0;dt<4;++dt) nm[dt] = f32x4{0.f,0.f,0.f,0.f};
        #pragma unroll
        for(int j=0;j<8;++j){
            bf16x8 af = *(const bf16x8*)&phi[16*w+c][32*j+8*g];
            #pragma unroll
            for(int dt=0;dt<4;++dt){
                const int row = 16*dt + c, cb = 4*j + g;
                bf16x8 bfr = *(const bf16x8*)(kvs + row*256 + ((cb ^ (row&7))*8));
                nm[dt] = MFMA(af, bfr, nm[dt]);
            }
        }
        #pragma unroll
        for(int dt=0;dt<4;++dt)
            #pragma unroll
            for(int r=0;r<4;++r){
                const int srow = s0 + 16*w + 4*g + r;
                attn[(size_t)(b*4096+srow)*1024 + h*64 + 16*dt + c] = f2bf(nm[dt][r]*8.f/den[r]);
            }
        __syncthreads();              // phi reads done before next tile's writes
    }
}

// ============================================================================
// k_out: out = attn(bf16) @ WfT(bf16) + bf, fp32 out. GEMM core v2.
// grid (64,4) = 256 = 1 exact CU round.
// ============================================================================
__global__ __launch_bounds__(512,2) void k_out(const u16* __restrict__ attn,
        const u16* __restrict__ Wh, const float* __restrict__ bfb, float* __restrict__ out){
    __shared__ u16 As[3*128*64];   // 48KB
    __shared__ u16 Bs[3*256*64];   // 96KB
    const int bx = blockIdx.x, by = blockIdx.y;
    const int tid = threadIdx.x, w = tid>>6, l = tid&63, g = l>>4, c = l&15;
    const int wr = w>>2, wc = w&3;
    const u16* Ap = attn + (size_t)bx*128*1024;
    const u16* Bp = Wh + (size_t)by*256*1024;
    f32x4 acc[4][4];
    #pragma unroll
    for(int mt=0;mt<4;++mt)
        #pragma unroll
        for(int nt=0;nt<4;++nt) acc[mt][nt] = f32x4{0.f,0.f,0.f,0.f};

    GEMM_CORE_128x256(As, Bs, Ap, Bp, acc);

    const int n0 = by*256 + 64*wc;
    #pragma unroll
    for(int mt=0;mt<4;++mt){
        const int rowb = bx*128 + 64*wr + 16*mt + 4*g;
        #pragma unroll
        for(int nt=0;nt<4;++nt){
            const float bb = bfb[n0+16*nt+c];
            #pragma unroll
            for(int r=0;r<4;++r)
                out[(size_t)(rowb+r)*1024 + n0 + 16*nt + c] = acc[mt][nt][r] + bb;
        }
    }
}

// ============================================================================
extern "C" void kernel_launch(void* const* d_in, const int* in_sizes, int n_in,
                              void* d_out, int out_size, void* d_ws, size_t ws_size,
                              hipStream_t stream){
    (void)in_sizes; (void)n_in; (void)out_size;
    const float* X    = (const float*)d_in[0];
    const float* mask = (const float*)d_in[1];
    const float* Wq   = (const float*)d_in[2];
    const float* bq   = (const float*)d_in[3];
    const float* Wk   = (const float*)d_in[4];
    const float* bk   = (const float*)d_in[5];
    const float* Wv   = (const float*)d_in[6];
    const float* bv   = (const float*)d_in[7];
    const float* Wf   = (const float*)d_in[8];
    const float* bfb  = (const float*)d_in[9];
    const float* proj = (const float*)d_in[10];
    float* out = (float*)d_out;

    char* w = (char*)d_ws;
    size_t off = 0;
    auto alloc = [&](size_t n)->void*{ void* p = w + off; off = (off + n + 255) & ~(size_t)255; return p; };
    u16*   Xb     = (u16*)  alloc((size_t)8192*1024*2);    // X bf16
    u16*   WT     = (u16*)  alloc((size_t)3*1048576*2);    // Wq,Wk,Wv transposed [n][k]
    u16*   Wfh    = (u16*)  alloc((size_t)1048576*2);      // WfT
    u16*   pPh    = (u16*)  alloc(16384*2);                // proj packed (bf16)
    u16*   Qb     = (u16*)  alloc((size_t)8192*1024*2);    // normalized Q bf16
    u16*   Kb     = (u16*)  alloc((size_t)8192*1024*2);    // normalized K bf16
    u16*   VT     = (u16*)  alloc((size_t)32*64*4096*2);   // V^T per head bf16
    float* KVpart = (float*)alloc((size_t)32*16*16384*4);  // split-K KV partials
    float* Zpart  = (float*)alloc((size_t)32*16*256*4);
    u16*   KVT    = (u16*)  alloc((size_t)32*64*256*2);    // KV^T [d][m] bf16
    float* Zr     = (float*)alloc((size_t)32*256*4);
    u16*   attnB  = (u16*)  alloc((size_t)8192*1024*2);    // attn bf16
    if (off > ws_size) return;  // ws too small: fail cleanly (output stays zero)

    k_prep<<<dim3(12352), 256, 0, stream>>>(X, Wq, Wk, Wv, Wf, proj, Xb, WT, Wfh, pPh);
    k_qkv<<<dim3(64,12), 512, 0, stream>>>(Xb, WT, bq, bk, bv, Qb, Kb, VT);
    k_kv<<<dim3(16,32), 256, 0, stream>>>(Kb, pPh, mask, VT, KVpart, Zpart);
    k_kvreduce<<<dim3(512), 256, 0, stream>>>(KVpart, Zpart, KVT, Zr);
    k_attn<<<dim3(8,32), 512, 0, stream>>>(Qb, pPh, KVT, Zr, attnB);
    k_out<<<dim3(64,4), 512, 0, stream>>>(attnB, Wfh, bfb, out);
}

// Round 15
// 157.112 us; speedup vs baseline: 1.6816x; 1.0904x over previous
//
#include <hip/hip_runtime.h>
#include <cmath>

typedef unsigned short u16;
typedef unsigned int   u32;
typedef __attribute__((ext_vector_type(8))) short bf16x8;  // 8 bf16 in 4 VGPRs
typedef __attribute__((ext_vector_type(4))) float f32x4;   // MFMA accumulator

#define DEV __device__ __forceinline__
#define MFMA(a,b,c) __builtin_amdgcn_mfma_f32_16x16x32_bf16((a),(b),(c),0,0,0)

// async global->LDS, 16B per lane: lane l writes dst + l*16 bytes (dst wave-uniform;
// global source address is PER-LANE)
#define GLOAD16(dst, src) __builtin_amdgcn_global_load_lds( \
    (const __attribute__((address_space(1))) void*)(src), \
    (__attribute__((address_space(3))) void*)(dst), 16, 0, 0)

// ---- bf16 helpers (RNE) ----
DEV u16 f2bf(float x){ union{float f;u32 u;} v; v.f=x; u32 r=v.u+0x7FFFu+((v.u>>16)&1u); return (u16)(r>>16); }
DEV float bf2f(u16 h){ union{u32 u;float f;} v; v.u=((u32)h)<<16; return v.f; }

// LDS read-side swizzle: within a row (64 elems = 8 col-blocks of 8), XOR the
// col-block with row&7. Same involution on the gload SOURCE col, LDS dest
// linear (rule #21). HW-verified rounds 7-14: conflicts=0, absmax unchanged.
DEV int swz(int row, int cb){ return row*64 + ((cb ^ (row&7))*8); }

// stage one 64x64 unit: 512 threads x 16B; dst linear, src col inverse-swizzled
#define STGU(arr, slotsz, slot, j, P, k0) GLOAD16( \
    &(arr)[(slot)*(slotsz) + ((j)*64 + w*8)*64], \
    (P) + (size_t)((j)*64 + srow_)*1024 + (k0) + scol_)

// ============================================================================
// GEMM core v2 (de-poisoned schedule, round-12): BM=128 x BN=256, BK=64,
// K=1024 (16 tiles), 512 thr = 8 waves (2M x 4N). 3 LDS slots, stage 2 tiles
// ahead (6 gloads/tile), vmcnt(6) once/tile, ONE barrier/tile.
// ============================================================================
#define GEMM_CORE_128x256(As, Bs, Ap, Bp, acc) do{ \
    const int srow_ = w*8 + (l>>3); \
    const int scol_ = ((l&7) ^ (l>>3))*8; \
    STGU(Bs,256*64,0,0,Bp,0); STGU(Bs,256*64,0,1,Bp,0); STGU(Bs,256*64,0,2,Bp,0); \
    STGU(Bs,256*64,0,3,Bp,0); STGU(As,128*64,0,0,Ap,0); STGU(As,128*64,0,1,Ap,0); \
    STGU(Bs,256*64,1,0,Bp,64); STGU(Bs,256*64,1,1,Bp,64); STGU(Bs,256*64,1,2,Bp,64); \
    STGU(Bs,256*64,1,3,Bp,64); STGU(As,128*64,1,0,Ap,64); STGU(As,128*64,1,1,Ap,64); \
    asm volatile("s_waitcnt vmcnt(6)" ::: "memory"); \
    __builtin_amdgcn_s_barrier(); \
    __builtin_amdgcn_sched_barrier(0); \
    for(int kt=0; kt<16; ++kt){ \
        const int sl = kt % 3; \
        const int st = (kt+2) % 3; \
        const int k2 = (kt+2)*64; \
        const u16* Asl = (As) + sl*(128*64); \
        const u16* Bsl = (Bs) + sl*(256*64); \
        bf16x8 bf_[4][2], af_[4][2]; \
        _Pragma("unroll") \
        for(int nt=0;nt<4;++nt) \
            _Pragma("unroll") \
            for(int ks=0;ks<2;++ks) \
                bf_[nt][ks] = *(const bf16x8*)&Bsl[swz(64*wc+16*nt+c, 4*ks+g)]; \
        _Pragma("unroll") \
        for(int mt=0;mt<4;++mt) \
            _Pragma("unroll") \
            for(int ks=0;ks<2;++ks) \
                af_[mt][ks] = *(const bf16x8*)&Asl[swz(64*wr+16*mt+c, 4*ks+g)]; \
        if (kt<=13){ STGU(Bs,256*64,st,0,Bp,k2); STGU(Bs,256*64,st,1,Bp,k2); STGU(Bs,256*64,st,2,Bp,k2); \
                     STGU(Bs,256*64,st,3,Bp,k2); STGU(As,128*64,st,0,Ap,k2); STGU(As,128*64,st,1,Ap,k2); } \
        _Pragma("unroll") \
        for(int mt=0;mt<4;++mt) \
            _Pragma("unroll") \
            for(int nt=0;nt<4;++nt) \
                _Pragma("unroll") \
                for(int ks=0;ks<2;++ks) \
                    acc[mt][nt] = MFMA(af_[mt][ks], bf_[nt][ks], acc[mt][nt]); \
        if (kt<=13)      { asm volatile("s_waitcnt vmcnt(6)" ::: "memory"); } \
        else if (kt==14) { asm volatile("s_waitcnt vmcnt(0)" ::: "memory"); } \
        __builtin_amdgcn_s_barrier(); \
        __builtin_amdgcn_sched_barrier(0); \
    } \
}while(0)

// ============================================================================
// k_prep: ALL prep fused into one dispatch.
// ============================================================================
__global__ __launch_bounds__(256) void k_prep(const float* __restrict__ X,
        const float* __restrict__ Wq, const float* __restrict__ Wk,
        const float* __restrict__ Wv, const float* __restrict__ Wf,
        const float* __restrict__ proj,
        u16* __restrict__ Xb, u16* __restrict__ WT, u16* __restrict__ Wfh,
        u16* __restrict__ pPh){
    const int bid = blockIdx.x, tid = threadIdx.x;
    if (bid < 4096){
        __shared__ float t[32][33];
        const int which = bid >> 10, bb = bid & 1023;
        const float* in = (which==0) ? Wq : (which==1) ? Wk : (which==2) ? Wv : Wf;
        u16* hi = (which==3) ? Wfh : (WT + (size_t)which*1048576);
        const int r0 = (bb>>5)*32, c0 = (bb&31)*32;
        const int lr = tid>>3, lc = (tid&7)*4;
        float4 v = *(const float4*)(in + (size_t)(r0+lr)*1024 + c0 + lc);
        t[lr][lc]=v.x; t[lr][lc+1]=v.y; t[lr][lc+2]=v.z; t[lr][lc+3]=v.w;
        __syncthreads();
        ushort4 o;
        o.x=f2bf(t[lc+0][lr]); o.y=f2bf(t[lc+1][lr]);
        o.z=f2bf(t[lc+2][lr]); o.w=f2bf(t[lc+3][lr]);
        *(ushort4*)(hi + (size_t)(c0+lr)*1024 + r0+lc) = o;
    } else if (bid < 12288){
        size_t i = ((size_t)(bid-4096)*256 + tid)*4;
        float4 v = *(const float4*)(X+i);
        ushort4 o; o.x=f2bf(v.x); o.y=f2bf(v.y); o.z=f2bf(v.z); o.w=f2bf(v.w);
        *(ushort4*)(Xb+i) = o;
    } else {
        int idx = (bid-12288)*256 + tid;          // 0..16383
        int e = idx&7, l = (idx>>3)&63, f = idx>>9;
        int nt = f>>1, ks = f&1;
        int d = 32*ks + 8*(l>>4) + e;
        int m = 16*nt + (l&15);
        pPh[idx] = f2bf(proj[d*256 + m]);
    }
}

// ============================================================================
// k_qkv: C = X @ {Wq,Wk,Wv}; GEMM core v2. grid (64,12) = 768 = 3 CU rounds.
// ============================================================================
__global__ __launch_bounds__(512,2) void k_qkv(const u16* __restrict__ Xb, const u16* __restrict__ WT,
        const float* __restrict__ bq, const float* __restrict__ bk, const float* __restrict__ bv,
        u16* __restrict__ Qb, u16* __restrict__ Kb, u16* __restrict__ VT){
    __shared__ u16 As[3*128*64];   // 48KB
    __shared__ u16 Bs[3*256*64];   // 96KB
    const int bx = blockIdx.x, y = blockIdx.y;
    const int wsel = y>>2, nb = y&3;
    const int tid = threadIdx.x, w = tid>>6, l = tid&63, g = l>>4, c = l&15;
    const int wr = w>>2, wc = w&3;
    const u16* Ap = Xb + (size_t)bx*128*1024;
    const u16* Bp = WT + (size_t)wsel*1048576 + (size_t)nb*256*1024;
    f32x4 acc[4][4];
    #pragma unroll
    for(int mt=0;mt<4;++mt)
        #pragma unroll
        for(int nt=0;nt<4;++nt) acc[mt][nt] = f32x4{0.f,0.f,0.f,0.f};

    GEMM_CORE_128x256(As, Bs, Ap, Bp, acc);

    const int n0 = nb*256 + 64*wc;    // col within this wsel's 1024
    const int b = bx>>5;
    if (wsel < 2){
        u16* Out = wsel ? Kb : Qb;
        const float* bias = wsel ? bk : bq;
        float bb[4];
        #pragma unroll
        for(int nt=0;nt<4;++nt) bb[nt] = bias[n0+16*nt+c];
        #pragma unroll
        for(int mt=0;mt<4;++mt){
            #pragma unroll
            for(int nt=0;nt<4;++nt)
                #pragma unroll
                for(int r=0;r<4;++r) acc[mt][nt][r] += bb[nt];
            // wave's 64 cols are one head -> norm over nt(4) x shfl16
            #pragma unroll
            for(int r=0;r<4;++r){
                float ss = 0.f;
                #pragma unroll
                for(int nt=0;nt<4;++nt){ float vv = acc[mt][nt][r]; ss += vv*vv; }
                ss += __shfl_xor(ss,1); ss += __shfl_xor(ss,2);
                ss += __shfl_xor(ss,4); ss += __shfl_xor(ss,8);
                float sc = 1.f/(sqrtf(ss)+1e-6f);
                #pragma unroll
                for(int nt=0;nt<4;++nt) acc[mt][nt][r] *= sc;
            }
            const int rowb = bx*128 + 64*wr + 16*mt + 4*g;
            #pragma unroll
            for(int nt=0;nt<4;++nt)
                #pragma unroll
                for(int r=0;r<4;++r)
                    Out[(size_t)(rowb+r)*1024 + n0 + 16*nt + c] = f2bf(acc[mt][nt][r]);
        }
    } else {
        const int h = nb*4 + wc;
        float bb[4];
        #pragma unroll
        for(int nt=0;nt<4;++nt) bb[nt] = bv[n0+16*nt+c];
        #pragma unroll
        for(int mt=0;mt<4;++mt)
            #pragma unroll
            for(int nt=0;nt<4;++nt){
                const int d = 16*nt + c;
                const int s0m = (bx&31)*128 + 64*wr + 16*mt + 4*g;
                ushort4 o;
                o.x = f2bf(acc[mt][nt][0]+bb[nt]); o.y = f2bf(acc[mt][nt][1]+bb[nt]);
                o.z = f2bf(acc[mt][nt][2]+bb[nt]); o.w = f2bf(acc[mt][nt][3]+bb[nt]);
                *(ushort4*)(VT + ((size_t)(b*16+h)*64 + d)*4096 + s0m) = o;
            }
    }
}

// ============================================================================
// k_kv v2: grid (8, 32) = 256 blocks = 1 CU round, 512 thr = 8 waves.
// Split-K 8 chunks of 512 s; 4 t-iters of 128 s-rows. pPh staged in LDS once
// (removes per-MFMA global B-fragment reads). Phase A: wave w -> s rows
// 16w..16w+15 per tile. Phase B: wave w owns m rows 32w..32w+31, kv[2][4].
// LDS: pps 32KB + phiT 69.6KB + Vs 17.4KB + zbuf 8KB = 125KB.
// ============================================================================
__global__ __launch_bounds__(512) void k_kv(const u16* __restrict__ Kb,
        const u16* __restrict__ pPh,
        const float* __restrict__ mask, const u16* __restrict__ VT,
        float* __restrict__ KVpart, float* __restrict__ Zpart){
    __shared__ u16 pps[16384];        // 32KB, linear copy of pPh
    __shared__ u16 phiT[256][136];    // [m][s 128], pad 136
    __shared__ u16 Vs[64][136];       // [d][s 128]
    __shared__ float zbuf[8][256];
    const int chunk = blockIdx.x, bh = blockIdx.y;
    const int b = bh>>4, h = bh&15;
    const int tid = threadIdx.x, w = tid>>6, l = tid&63, g = l>>4, c = l&15;
    // stage pps once
    #pragma unroll
    for(int j2=0;j2<4;++j2){
        const int base = (j2*8 + w)*512;
        GLOAD16(pps + base, pPh + base + l*8);
    }
    f32x4 kv[2][4];
    #pragma unroll
    for(int mt=0;mt<2;++mt) for(int dt=0;dt<4;++dt) kv[mt][dt] = f32x4{0.f,0.f,0.f,0.f};
    float zacc[16];
    #pragma unroll
    for(int nt=0;nt<16;++nt) zacc[nt]=0.f;
    const int vd = tid>>3, vs8 = (tid&7)*16;
    asm volatile("s_waitcnt vmcnt(0)" ::: "memory");
    __syncthreads();                       // pps staged
    for(int t=0;t<4;++t){
        const int s0 = chunk*512 + t*128;
        { // stage V tile [64 d][128 s] (reg path; 512 thr x 16 u16)
            const u16* pv = VT + ((size_t)bh*64 + vd)*4096 + s0 + vs8;
            uint4 v0 = *(const uint4*)pv, v1 = *(const uint4*)(pv+8);
            *(uint4*)&Vs[vd][vs8] = v0; *(uint4*)&Vs[vd][vs8+8] = v1;
        }
        // phase A: u = K_head @ proj (wave w -> s rows s0+16w..+15), pps-resident
        f32x4 ph[16];
        #pragma unroll
        for(int nt=0;nt<16;++nt) ph[nt] = f32x4{0.f,0.f,0.f,0.f};
        #pragma unroll
        for(int ks=0;ks<2;++ks){
            const int srow = s0 + 16*w + c;
            bf16x8 ah = *(const bf16x8*)(Kb + (size_t)(b*4096+srow)*1024 + h*64 + 32*ks + 8*g);
            #pragma unroll
            for(int nt=0;nt<16;++nt){
                bf16x8 bh8 = *(const bf16x8*)(pps + ((nt*2+ks)*64 + l)*8);
                ph[nt] = MFMA(ah, bh8, ph[nt]);
            }
        }
        float mk[4];
        #pragma unroll
        for(int r=0;r<4;++r) mk[r] = mask[b*4096 + s0 + 16*w + 4*g + r];
        #pragma unroll
        for(int nt=0;nt<16;++nt){
            float zs = 0.f;
            #pragma unroll
            for(int r=0;r<4;++r){
                float phv = __expf(ph[nt][r]-0.5f)*0.0625f*mk[r];
                phiT[c+16*nt][16*w+4*g+r] = f2bf(phv);
                zs += phv;
            }
            zacc[nt] += zs;
        }
        __syncthreads();               // phiT + Vs written
        // phase B: KV += phiT(A, m rows 32w..) x Vs(B, d cols), K=128
        #pragma unroll
        for(int ks=0;ks<4;++ks){
            bf16x8 afr[2], bfr[4];
            #pragma unroll
            for(int mt=0;mt<2;++mt) afr[mt] = *(const bf16x8*)&phiT[32*w+16*mt+c][32*ks+8*g];
            #pragma unroll
            for(int dt=0;dt<4;++dt) bfr[dt] = *(const bf16x8*)&Vs[16*dt+c][32*ks+8*g];
            #pragma unroll
            for(int mt=0;mt<2;++mt)
                #pragma unroll
                for(int dt=0;dt<4;++dt)
                    kv[mt][dt] = MFMA(afr[mt], bfr[dt], kv[mt][dt]);
        }
        __syncthreads();               // phase-B reads done before next overwrite
    }
    // Z partial
    #pragma unroll
    for(int nt=0;nt<16;++nt){
        float z = zacc[nt];
        z += __shfl_xor(z,16); z += __shfl_xor(z,32);
        if (g==0) zbuf[w][c+16*nt] = z;
    }
    __syncthreads();
    if (tid < 256){
        float z = 0.f;
        #pragma unroll
        for(int ww=0;ww<8;++ww) z += zbuf[ww][tid];
        Zpart[((size_t)bh*8+chunk)*256 + tid] = z;
    }
    float* kout = KVpart + ((size_t)bh*8+chunk)*16384;   // [256 m][64 d]
    #pragma unroll
    for(int mt=0;mt<2;++mt)
        #pragma unroll
        for(int dt=0;dt<4;++dt)
            #pragma unroll
            for(int r=0;r<4;++r)
                kout[(32*w+16*mt+4*g+r)*64 + 16*dt + c] = kv[mt][dt][r];
}

// ============================================================================
// k_kvreduce (parallel): 512 blocks x 256 threads, one float4 of KV per thread.
// 8 split-K chunks.
// ============================================================================
__global__ __launch_bounds__(256) void k_kvreduce(const float* __restrict__ KVpart,
        const float* __restrict__ Zpart, u16* __restrict__ KVT, float* __restrict__ Z){
    const int gid = blockIdx.x*256 + threadIdx.x;      // 0..131071
    const int bh = gid >> 12;                          // 4096 float4 per bh
    const int i0 = (gid & 4095) * 4;                   // element idx in [256m][64d]
    float4 s = {0.f,0.f,0.f,0.f};
    const float* base = KVpart + (size_t)bh*8*16384 + i0;
    #pragma unroll
    for(int ch=0; ch<8; ++ch){
        float4 v = *(const float4*)(base + (size_t)ch*16384);
        s.x+=v.x; s.y+=v.y; s.z+=v.z; s.w+=v.w;
    }
    const int m = i0 >> 6, d = i0 & 63;                // 4 consecutive d, same m
    u16* dst = KVT + ((size_t)bh*64 + d)*256 + m;
    dst[0]   = f2bf(s.x);
    dst[256] = f2bf(s.y);
    dst[512] = f2bf(s.z);
    dst[768] = f2bf(s.w);
    if (gid < 8192){
        const int zbh = gid >> 8, zm = gid & 255;
        float z = 0.f;
        #pragma unroll
        for(int ch=0; ch<8; ++ch) z += Zpart[((size_t)zbh*8+ch)*256 + zm];
        Z[zbh*256 + zm] = z;
    }
}

// ============================================================================
// k_attn v2 (round-14 proven): grid (8, 32) = 256 blocks, 512 thr = 8 waves.
// KVT (32KB swizzled) + pPh (32KB) + Z staged in LDS once; 4 tiles x 128 rows.
// ============================================================================
__global__ __launch_bounds__(512) void k_attn(const u16* __restrict__ Qb,
        const u16* __restrict__ pPh,
        const u16* __restrict__ KVT, const float* __restrict__ Z, u16* __restrict__ attn){
    __shared__ u16 kvs[64*256];       // 32KB, row d, swizzled col-blocks
    __shared__ u16 pps[16384];        // 32KB, linear copy of pPh
    __shared__ u16 phi[128][264];     // 67.5KB
    __shared__ float Zs[256];
    const int bx = blockIdx.x, bh = blockIdx.y;
    const int b = bh>>4, h = bh&15;
    const int tid = threadIdx.x, w = tid>>6, l = tid&63, g = l>>4, c = l&15;
    if (tid < 256) Zs[tid] = Z[bh*256 + tid];
    // stage kvs: 32 gload units of 2 rows; dst linear, src col-block pre-swizzled
    #pragma unroll
    for(int j2=0;j2<4;++j2){
        const int base_row = (j2*8 + w)*2;
        const int row = base_row + (l>>5), cb = l&31;
        GLOAD16(kvs + base_row*256,
                KVT + (size_t)bh*16384 + row*256 + ((cb ^ (row&7))*8));
    }
    // stage pps: straight linear copy
    #pragma unroll
    for(int j2=0;j2<4;++j2){
        const int base = (j2*8 + w)*512;
        GLOAD16(pps + base, pPh + base + l*8);
    }
    asm volatile("s_waitcnt vmcnt(0)" ::: "memory");
    __syncthreads();

    for(int t=0;t<4;++t){
        const int s0 = bx*512 + t*128;
        // phiQ: u = Q_head @ proj (wave w -> s rows s0+16w .. +15)
        f32x4 ph[16];
        #pragma unroll
        for(int nt=0;nt<16;++nt) ph[nt] = f32x4{0.f,0.f,0.f,0.f};
        #pragma unroll
        for(int ks=0;ks<2;++ks){
            const int srow = s0 + 16*w + c;
            bf16x8 ah = *(const bf16x8*)(Qb + (size_t)(b*4096+srow)*1024 + h*64 + 32*ks + 8*g);
            #pragma unroll
            for(int nt=0;nt<16;++nt){
                bf16x8 bh8 = *(const bf16x8*)(pps + ((nt*2+ks)*64 + l)*8);
                ph[nt] = MFMA(ah, bh8, ph[nt]);
            }
        }
        float den[4] = {0.f,0.f,0.f,0.f};
        #pragma unroll
        for(int nt=0;nt<16;++nt){
            float zv = Zs[c+16*nt];
            #pragma unroll
            for(int r=0;r<4;++r){
                float phv = __expf(ph[nt][r]-0.5f)*0.0625f;
                den[r] += phv*zv;
                phi[16*w+4*g+r][c+16*nt] = f2bf(phv);
            }
        }
        #pragma unroll
        for(int r=0;r<4;++r){
            den[r] += __shfl_xor(den[r],1); den[r] += __shfl_xor(den[r],2);
            den[r] += __shfl_xor(den[r],4); den[r] += __shfl_xor(den[r],8);
            den[r] += 1e-6f;
        }
        __syncthreads();              // phi written
        f32x4 nm[4];
        #pragma unroll
        for(int dt=0;dt<4;++dt) nm[dt] = f32x4{0.f,0.f,0.f,0.f};
        #pragma unroll
        for(int j=0;j<8;++j){
            bf16x8 af = *(const bf16x8*)&phi[16*w+c][32*j+8*g];
            #pragma unroll
            for(int dt=0;dt<4;++dt){
                const int row = 16*dt + c, cb = 4*j + g;
                bf16x8 bfr = *(const bf16x8*)(kvs + row*256 + ((cb ^ (row&7))*8));
                nm[dt] = MFMA(af, bfr, nm[dt]);
            }
        }
        #pragma unroll
        for(int dt=0;dt<4;++dt)
            #pragma unroll
            for(int r=0;r<4;++r){
                const int srow = s0 + 16*w + 4*g + r;
                attn[(size_t)(b*4096+srow)*1024 + h*64 + 16*dt + c] = f2bf(nm[dt][r]*8.f/den[r]);
            }
        __syncthreads();              // phi reads done before next tile's writes
    }
}

// ============================================================================
// k_out: out = attn(bf16) @ WfT(bf16) + bf, fp32 out. GEMM core v2.
// grid (64,4) = 256 = 1 exact CU round.
// ============================================================================
__global__ __launch_bounds__(512,2) void k_out(const u16* __restrict__ attn,
        const u16* __restrict__ Wh, const float* __restrict__ bfb, float* __restrict__ out){
    __shared__ u16 As[3*128*64];   // 48KB
    __shared__ u16 Bs[3*256*64];   // 96KB
    const int bx = blockIdx.x, by = blockIdx.y;
    const int tid = threadIdx.x, w = tid>>6, l = tid&63, g = l>>4, c = l&15;
    const int wr = w>>2, wc = w&3;
    const u16* Ap = attn + (size_t)bx*128*1024;
    const u16* Bp = Wh + (size_t)by*256*1024;
    f32x4 acc[4][4];
    #pragma unroll
    for(int mt=0;mt<4;++mt)
        #pragma unroll
        for(int nt=0;nt<4;++nt) acc[mt][nt] = f32x4{0.f,0.f,0.f,0.f};

    GEMM_CORE_128x256(As, Bs, Ap, Bp, acc);

    const int n0 = by*256 + 64*wc;
    #pragma unroll
    for(int mt=0;mt<4;++mt){
        const int rowb = bx*128 + 64*wr + 16*mt + 4*g;
        #pragma unroll
        for(int nt=0;nt<4;++nt){
            const float bb = bfb[n0+16*nt+c];
            #pragma unroll
            for(int r=0;r<4;++r)
                out[(size_t)(rowb+r)*1024 + n0 + 16*nt + c] = acc[mt][nt][r] + bb;
        }
    }
}

// ============================================================================
extern "C" void kernel_launch(void* const* d_in, const int* in_sizes, int n_in,
                              void* d_out, int out_size, void* d_ws, size_t ws_size,
                              hipStream_t stream){
    (void)in_sizes; (void)n_in; (void)out_size;
    const float* X    = (const float*)d_in[0];
    const float* mask = (const float*)d_in[1];
    const float* Wq   = (const float*)d_in[2];
    const float* bq   = (const float*)d_in[3];
    const float* Wk   = (const float*)d_in[4];
    const float* bk   = (const float*)d_in[5];
    const float* Wv   = (const float*)d_in[6];
    const float* bv   = (const float*)d_in[7];
    const float* Wf   = (const float*)d_in[8];
    const float* bfb  = (const float*)d_in[9];
    const float* proj = (const float*)d_in[10];
    float* out = (float*)d_out;

    char* w = (char*)d_ws;
    size_t off = 0;
    auto alloc = [&](size_t n)->void*{ void* p = w + off; off = (off + n + 255) & ~(size_t)255; return p; };
    u16*   Xb     = (u16*)  alloc((size_t)8192*1024*2);    // X bf16
    u16*   WT     = (u16*)  alloc((size_t)3*1048576*2);    // Wq,Wk,Wv transposed [n][k]
    u16*   Wfh    = (u16*)  alloc((size_t)1048576*2);      // WfT
    u16*   pPh    = (u16*)  alloc(16384*2);                // proj packed (bf16)
    u16*   Qb     = (u16*)  alloc((size_t)8192*1024*2);    // normalized Q bf16
    u16*   Kb     = (u16*)  alloc((size_t)8192*1024*2);    // normalized K bf16
    u16*   VT     = (u16*)  alloc((size_t)32*64*4096*2);   // V^T per head bf16
    float* KVpart = (float*)alloc((size_t)32*8*16384*4);   // split-K KV partials
    float* Zpart  = (float*)alloc((size_t)32*8*256*4);
    u16*   KVT    = (u16*)  alloc((size_t)32*64*256*2);    // KV^T [d][m] bf16
    float* Zr     = (float*)alloc((size_t)32*256*4);
    u16*   attnB  = (u16*)  alloc((size_t)8192*1024*2);    // attn bf16
    if (off > ws_size) return;  // ws too small: fail cleanly (output stays zero)

    k_prep<<<dim3(12352), 256, 0, stream>>>(X, Wq, Wk, Wv, Wf, proj, Xb, WT, Wfh, pPh);
    k_qkv<<<dim3(64,12), 512, 0, stream>>>(Xb, WT, bq, bk, bv, Qb, Kb, VT);
    k_kv<<<dim3(8,32), 512, 0, stream>>>(Kb, pPh, mask, VT, KVpart, Zpart);
    k_kvreduce<<<dim3(512), 256, 0, stream>>>(KVpart, Zpart, KVT, Zr);
    k_attn<<<dim3(8,32), 512, 0, stream>>>(Qb, pPh, KVT, Zr, attnB);
    k_out<<<dim3(64,4), 512, 0, stream>>>(attnB, Wfh, bfb, out);
}